// Round 9
// baseline (171.561 us; speedup 1.0000x reference)
//
#include <hip/hip_runtime.h>
#include <hip/hip_fp16.h>
#include <math.h>

// Problem constants
#define T_LEN 131072
#define NCH   32
#define NBAT  4
#define WIN   512
#define HOP   256
#define NFR   512            // frames per (b,c) = T/HOP
#define NBIN  257            // rfft bins
#define NBC   (NBAT*NCH)     // 128
#define FPB   8              // frames per chunk (one wave per chunk)
#define NBLK  (NFR/FPB)      // 64 chunks per bc
#define TWOPI 6.28318530717958647692f

// XOR swizzle for FFT LDS float2 arrays (hits the b64 4-lane/bank floor)
#define SWZ(m) ((m) ^ ((((m) >> 4) & 15)))

__device__ __forceinline__ float2 cmul(float2 u, float2 v) {
  return make_float2(fmaf(u.x, v.x, -u.y * v.y), fmaf(u.x, v.y, u.y * v.x));
}

__device__ __forceinline__ float fast_tanh(float x) {
  float e = __expf(2.0f * x);                    // inf-safe
  return 1.0f - 2.0f * __builtin_amdgcn_rcpf(e + 1.0f);
}

__device__ __forceinline__ float2 h2f(__half2 h) { return __half22float2(h); }
__device__ __forceinline__ __half2 f2h(float2 f) { return __float22half2_rn(f); }

// Wave-level ordering fence: LDS ops of a wave execute in order on the DS
// pipe; this only stops compiler reordering (no s_barrier, no cnt drain).
// NOTE: the memory clobber also PINS global loads — issue prefetches BEFORE
// the compute region so they stay in flight across these fences.
__device__ __forceinline__ void wave_sync() {
  asm volatile("" ::: "memory");
  __builtin_amdgcn_wave_barrier();
  asm volatile("" ::: "memory");
}

// radix-4 DIF butterfly
__device__ __forceinline__ void r4bf(float2 a, float2 b, float2 c, float2 d,
                                     float2& y0, float2& t1, float2& t2, float2& t3) {
  float2 apc = make_float2(a.x + c.x, a.y + c.y);
  float2 amc = make_float2(a.x - c.x, a.y - c.y);
  float2 bpd = make_float2(b.x + d.x, b.y + d.y);
  float2 bmd = make_float2(b.x - d.x, b.y - d.y);
  y0 = make_float2(apc.x + bpd.x, apc.y + bpd.y);
  t1 = make_float2(amc.x + bmd.y, amc.y - bmd.x);  // amc - i*bmd
  t2 = make_float2(apc.x - bpd.x, apc.y - bpd.y);
  t3 = make_float2(amc.x - bmd.y, amc.y + bmd.x);  // amc + i*bmd
}

struct TW {
  float2 a1, a2, a3, b1, b2, b3, c1, c2, c3;
};

__device__ __forceinline__ void load_tw(const float2* __restrict__ W256f, int lane, TW& t) {
  t.a1 = W256f[lane];     t.a2 = W256f[2 * lane];  t.a3 = W256f[3 * lane];
  int p1 = 4 * (lane >> 2);
  t.b1 = W256f[p1];       t.b2 = W256f[2 * p1];    t.b3 = W256f[3 * p1];
  int p2 = 16 * (lane >> 4);
  t.c1 = W256f[p2];       t.c2 = W256f[2 * p2];    t.c3 = W256f[3 * p2];
}

// 256-pt forward complex FFT. Input regs z0..z3 = z[lane+64m]; output regs
// z0..z3 = Z[lane+64m]. Stages 0 & 3 in registers; 1 & 2 via wave-private LDS.
__device__ __forceinline__ void fft256_reg(float2& z0, float2& z1, float2& z2, float2& z3,
                                           float2* __restrict__ buf, int lane, const TW& tw) {
  float2 y0, t1, t2, t3;
  // stage 0 (s=1, p=lane): pure register butterfly, scatter 4l..4l+3
  r4bf(z0, z1, z2, z3, y0, t1, t2, t3);
  int o0 = 4 * lane;
  buf[SWZ(o0)]     = y0;
  buf[SWZ(o0 + 1)] = cmul(tw.a1, t1);
  buf[SWZ(o0 + 2)] = cmul(tw.a2, t2);
  buf[SWZ(o0 + 3)] = cmul(tw.a3, t3);
  wave_sync();
  // stage 1 (s=4)
  {
    float2 a = buf[SWZ(lane)], b = buf[SWZ(lane + 64)],
           c = buf[SWZ(lane + 128)], d = buf[SWZ(lane + 192)];
    wave_sync();
    r4bf(a, b, c, d, y0, t1, t2, t3);
    int o = lane + 12 * (lane >> 2);
    buf[SWZ(o)]      = y0;
    buf[SWZ(o + 4)]  = cmul(tw.b1, t1);
    buf[SWZ(o + 8)]  = cmul(tw.b2, t2);
    buf[SWZ(o + 12)] = cmul(tw.b3, t3);
  }
  wave_sync();
  // stage 2 (s=16)
  {
    float2 a = buf[SWZ(lane)], b = buf[SWZ(lane + 64)],
           c = buf[SWZ(lane + 128)], d = buf[SWZ(lane + 192)];
    wave_sync();
    r4bf(a, b, c, d, y0, t1, t2, t3);
    int o = lane + 48 * (lane >> 4);
    buf[SWZ(o)]      = y0;
    buf[SWZ(o + 16)] = cmul(tw.c1, t1);
    buf[SWZ(o + 32)] = cmul(tw.c2, t2);
    buf[SWZ(o + 48)] = cmul(tw.c3, t3);
  }
  wave_sync();
  // stage 3 (s=64, p=0, twiddle-free): outputs land in register layout
  {
    float2 a = buf[SWZ(lane)], b = buf[SWZ(lane + 64)],
           c = buf[SWZ(lane + 128)], d = buf[SWZ(lane + 192)];
    wave_sync();
    r4bf(a, b, c, d, z0, z1, z2, z3);
  }
}

// W256f[m] = exp(-2pi i m/256), m<256 ; W512s[k] = exp(-2pi i k/512), k<=256
__device__ __forceinline__ void build_tables(float2* W256f, float2* W512s) {
  int tid = threadIdx.x;
  float sv, cv;
  __sincosf(-(TWOPI / 256.0f) * (float)tid, &sv, &cv);
  W256f[tid] = make_float2(cv, sv);
  __sincosf(-(TWOPI / 512.0f) * (float)tid, &sv, &cv);
  W512s[tid] = make_float2(cv, sv);
  if (tid == 0) W512s[256] = make_float2(-1.f, 0.f);
}

// ---------------------------------------------------------------------------
// 1) channel mix: y[b,d,t] = sum_c x[b,c,t] * mixer[c,d]   (fp16 output)
// ---------------------------------------------------------------------------
__global__ __launch_bounds__(256) void mix_kernel(const float* __restrict__ x,
                                                  const float* __restrict__ mixer,
                                                  __half2* __restrict__ y) {
  __shared__ float mm[NCH][NCH];
  for (int i = threadIdx.x; i < NCH * NCH; i += 256)
    ((float*)mm)[i] = mixer[i];
  __syncthreads();
  int b = blockIdx.y;
  int t2 = blockIdx.x * 256 + threadIdx.x;     // float2-pair index
  const float2* xv = (const float2*)x;
  float2 xr[NCH];
#pragma unroll
  for (int c = 0; c < NCH; c++)
    xr[c] = xv[(((size_t)(b * NCH + c)) * T_LEN >> 1) + t2];
#pragma unroll 4
  for (int d = 0; d < NCH; d++) {
    float ax = 0.f, ay = 0.f;
#pragma unroll
    for (int c = 0; c < NCH; c++) {
      ax = fmaf(xr[c].x, mm[c][d], ax);
      ay = fmaf(xr[c].y, mm[c][d], ay);
    }
    y[(((size_t)(b * NCH + d)) * T_LEN >> 1) + t2] = f2h(make_float2(ax, ay));
  }
}

// ---------------------------------------------------------------------------
// 2) forward rfft(512) + register-local scan. Wave = one 8-frame chunk.
//    Untangle 0.5's dropped (spec carries a uniform 2x scale, absorbed in inv).
//    Next-frame y loads prefetched before current frame's FFT.
// ---------------------------------------------------------------------------
__global__ __launch_bounds__(256, 4) void fft_fwd_kernel(const __half2* __restrict__ y,
                                                         const float* __restrict__ transfer,
                                                         __half2* __restrict__ spec) {
  __shared__ float2 fbuf[4][NBIN];       // wave-private FFT/mirror buffer
  __shared__ float2 W256f[256];
  __shared__ float2 W512s[NBIN];
  build_tables(W256f, W512s);
  __syncthreads();
  int wave = threadIdx.x >> 6, lane = threadIdx.x & 63;
  int cid = blockIdx.x * 4 + wave;       // chunk id 0..8191
  int bc = cid >> 6, blk = cid & (NBLK - 1);
  int ch = bc & (NCH - 1);
  float2* buf = fbuf[wave];
  TW tw; load_tw(W256f, lane, tw);
  float cwq[4], swq[4], trq[4];
#pragma unroll
  for (int q = 0; q < 4; q++) {
    int k = lane + 64 * q;
    cwq[q] = W512s[k].x; swq[q] = W512s[k].y;
    trq[q] = transfer[ch * NBIN + k];
  }
  float tr256 = transfer[ch * NBIN + 256];
  float2 s[4] = {make_float2(0,0), make_float2(0,0), make_float2(0,0), make_float2(0,0)};
  float s256x = 0.f;
  size_t base2 = ((size_t)bc * T_LEN + (size_t)blk * (FPB * HOP)) >> 1;  // half2 idx
  size_t fb = ((size_t)bc * NFR + (size_t)blk * FPB) * NBIN;
  bool lastchunk = (blk == NBLK - 1);
  const __half2* src = y + base2;
  // preload frame 0
  float2 c0 = h2f(src[lane]);
  float2 c1 = h2f(src[lane + 64]);
  float2 c2 = h2f(src[lane + 128]);
  float2 c3 = h2f(src[lane + 192]);
#pragma unroll 2
  for (int j = 0; j < FPB; ++j) {
    // prefetch frame j+1 (stays in flight across wave_sync fences)
    float2 n0, n1, n2, n3;
    bool have_next = (j + 1 < FPB);
    if (have_next) {
      const __half2* s2 = src + (size_t)(j + 1) * (HOP / 2);
      n0 = h2f(s2[lane]);
      n1 = h2f(s2[lane + 64]);
      if (lastchunk && (j + 1 == FPB - 1)) {
        n2 = make_float2(0, 0); n3 = make_float2(0, 0);
      } else {
        n2 = h2f(s2[lane + 128]);
        n3 = h2f(s2[lane + 192]);
      }
    }
    float2 z0 = c0, z1 = c1, z2 = c2, z3 = c3;
    fft256_reg(z0, z1, z2, z3, buf, lane, tw);
    // mirror staging
    buf[lane] = z0; buf[lane + 64] = z1; buf[lane + 128] = z2; buf[lane + 192] = z3;
    wave_sync();
    float2 zm0 = buf[(256 - lane) & 255];
    float2 zm1 = buf[192 - lane];
    float2 zm2 = buf[128 - lane];
    float2 zm3 = buf[64 - lane];
    float2 z0b = buf[0];
    wave_sync();
    // untangle (0.5's folded out -> 2x scale) + scan + store, k = lane+64q
#pragma unroll
    for (int q = 0; q < 4; q++) {
      float2 zk  = (q == 0) ? z0 : (q == 1) ? z1 : (q == 2) ? z2 : z3;
      float2 zmk = (q == 0) ? zm0 : (q == 1) ? zm1 : (q == 2) ? zm2 : zm3;
      float Ex = zk.x + zmk.x, Ey = zk.y - zmk.y;
      float dx = zk.x - zmk.x, dy = zk.y + zmk.y;
      float Ox = dy, Oy = -dx;
      float Yx = Ex + Ox * cwq[q] - Oy * swq[q];
      float Yy = Ey + Ox * swq[q] + Oy * cwq[q];
      s[q].x = trq[q] * (Yx + s[q].x);
      s[q].y = trq[q] * (Yy + s[q].y);
      spec[fb + (size_t)j * NBIN + lane + 64 * q] = f2h(s[q]);
    }
    // bin 256 (2x scale to match): Y = 2*(Z0.x - Z0.y)
    s256x = tr256 * (2.0f * (z0b.x - z0b.y) + s256x);
    if (lane == 0) spec[fb + (size_t)j * NBIN + 256] = f2h(make_float2(s256x, 0.f));
    wave_sync();
    if (have_next) { c0 = n0; c1 = n1; c2 = n2; c3 = n3; }
  }
}

// ---------------------------------------------------------------------------
// 3) carry scan across chunks: C[0]=0; C[i] = final[i-1] + tr^FPB * C[i-1]
// ---------------------------------------------------------------------------
__global__ __launch_bounds__(256) void carry_kernel(const __half2* __restrict__ spec,
                                                    const float* __restrict__ transfer,
                                                    __half2* __restrict__ carries) {
  int tid = blockIdx.x * 256 + threadIdx.x;
  if (tid >= NBC * NBIN) return;
  int bc = tid / NBIN, k = tid - bc * NBIN;
  int ch = bc & (NCH - 1);
  float tr = transfer[ch * NBIN + k];
  float tr2 = tr * tr;
  float tr4 = tr2 * tr2;
  float tr8 = tr4 * tr4;          // tr^FPB
  const __half2* fin = spec + (size_t)bc * NFR * NBIN + (size_t)(FPB - 1) * NBIN + k;
  __half2* cp = carries + (size_t)bc * NBLK * NBIN + k;
  float cx = 0.f, cy = 0.f;
  for (int i = 0; i < NBLK; i += 16) {
    float2 v[16];
#pragma unroll
    for (int u = 0; u < 16; u++) v[u] = h2f(fin[(size_t)(i + u) * FPB * NBIN]);
#pragma unroll
    for (int u = 0; u < 16; u++) {
      cp[(size_t)(i + u) * NBIN] = f2h(make_float2(cx, cy));
      cx = v[u].x + tr8 * cx;
      cy = v[u].y + tr8 * cy;
    }
  }
}

// ---------------------------------------------------------------------------
// 4) inverse rfft + hann + register OLA. Wave = one 8-frame chunk.
//    Untangle 0.5's dropped; total 4x scale absorbed into hann (1/1024).
//    Next-frame spec loads prefetched before current frame's work.
// ---------------------------------------------------------------------------
__global__ __launch_bounds__(256, 4) void fft_inv_kernel(const __half2* __restrict__ spec,
                                                         const __half2* __restrict__ carries,
                                                         const float* __restrict__ transfer,
                                                         const float* __restrict__ gain,
                                                         float* __restrict__ out,
                                                         __half2* __restrict__ bnd) {
  __shared__ float2 fbuf[4][NBIN];
  __shared__ float2 W256f[256];
  __shared__ float2 W512s[NBIN];
  build_tables(W256f, W512s);
  __syncthreads();
  int wave = threadIdx.x >> 6, lane = threadIdx.x & 63;
  int cid = blockIdx.x * 4 + wave;
  int bc = cid >> 6, blk = cid & (NBLK - 1);
  int ch = bc & (NCH - 1);
  float2* buf = fbuf[wave];
  TW tw; load_tw(W256f, lane, tw);
  const __half2* crp = carries + ((size_t)bc * NBLK + blk) * NBIN;
  float cwq[4], swq[4], trq[4], trp[4], h0[4], h1[4];
  float2 cv[4];
#pragma unroll
  for (int q = 0; q < 4; q++) {
    int k = lane + 64 * q;
    cwq[q] = W512s[k].x; swq[q] = -W512s[k].y;   // exp(+2pi i k/512)
    trq[q] = transfer[ch * NBIN + k];
    trp[q] = trq[q];
    cv[q] = h2f(crp[k]);
    int t0 = 2 * k, t1 = 2 * k + 1;
    int i0 = (t0 <= 256) ? t0 : 512 - t0;
    int i1 = (t1 <= 256) ? t1 : 512 - t1;
    h0[q] = (0.5f - 0.5f * W512s[i0].x) * (1.0f / 1024.0f);   // 1/256 and 1/4 scale
    h1[q] = (0.5f - 0.5f * W512s[i1].x) * (1.0f / 1024.0f);
  }
  float tr256 = transfer[ch * NBIN + 256], trp256 = tr256;
  float2 cv256 = h2f(crp[256]);
  float g = gain[ch];
  const __half2* sp0 = spec + ((size_t)bc * NFR + (size_t)blk * FPB) * NBIN;
  float2* outv = (float2*)out;
  size_t obase2 = ((size_t)bc * T_LEN + (size_t)blk * (FPB * HOP)) >> 1;
  __half2* bp = bnd + (((size_t)bc * NBLK + blk) * 2) * (HOP / 2);
  float2 pt0, pt1;                        // previous frame's windowed tail
  // preload frame 0
  float2 C0 = h2f(sp0[lane]);
  float2 C1 = h2f(sp0[lane + 64]);
  float2 C2 = h2f(sp0[lane + 128]);
  float2 C3 = h2f(sp0[lane + 192]);
  float2 C256 = h2f(sp0[256]);
#pragma unroll 2
  for (int j = 0; j < FPB; ++j) {
    // prefetch frame j+1 (stays in flight across wave_sync fences)
    float2 N0, N1, N2, N3, N256;
    bool have_next = (j + 1 < FPB);
    if (have_next) {
      const __half2* sp = sp0 + (size_t)(j + 1) * NBIN;
      N0 = h2f(sp[lane]);
      N1 = h2f(sp[lane + 64]);
      N2 = h2f(sp[lane + 128]);
      N3 = h2f(sp[lane + 192]);
      N256 = h2f(sp[256]);
    }
    // carry fix-up: O = local + tr^(j+1) * carry
    float2 Y0 = C0; Y0.x = fmaf(trp[0], cv[0].x, Y0.x); Y0.y = fmaf(trp[0], cv[0].y, Y0.y);
    float2 Y1 = C1; Y1.x = fmaf(trp[1], cv[1].x, Y1.x); Y1.y = fmaf(trp[1], cv[1].y, Y1.y);
    float2 Y2 = C2; Y2.x = fmaf(trp[2], cv[2].x, Y2.x); Y2.y = fmaf(trp[2], cv[2].y, Y2.y);
    float2 Y3 = C3; Y3.x = fmaf(trp[3], cv[3].x, Y3.x); Y3.y = fmaf(trp[3], cv[3].y, Y3.y);
    float2 y256 = C256;
    y256.x = fmaf(trp256, cv256.x, y256.x);
    y256.y = fmaf(trp256, cv256.y, y256.y);
#pragma unroll
    for (int q = 0; q < 4; q++) trp[q] *= trq[q];
    trp256 *= tr256;
    // mirror staging
    buf[lane] = Y0; buf[lane + 64] = Y1; buf[lane + 128] = Y2; buf[lane + 192] = Y3;
    if (lane == 0) buf[256] = y256;
    wave_sync();
    float2 ym0 = buf[256 - lane];
    float2 ym1 = buf[192 - lane];
    float2 ym2 = buf[128 - lane];
    float2 ym3 = buf[64 - lane];
    wave_sync();
    // inverse untangle (0.5's folded into h) -> conj'd FFT input
    float2 z0, z1, z2, z3;
#pragma unroll
    for (int q = 0; q < 4; q++) {
      float2 yk  = (q == 0) ? Y0 : (q == 1) ? Y1 : (q == 2) ? Y2 : Y3;
      float2 ymk = (q == 0) ? ym0 : (q == 1) ? ym1 : (q == 2) ? ym2 : ym3;
      float Ex = yk.x + ymk.x, Ey = yk.y - ymk.y;
      float dx = yk.x - ymk.x, dy = yk.y + ymk.y;
      float Ox = dx * cwq[q] - dy * swq[q];
      float Oy = dx * swq[q] + dy * cwq[q];
      float2 zq = make_float2(Ex - Oy, -(Ey + Ox));
      if (q == 0) z0 = zq; else if (q == 1) z1 = zq; else if (q == 2) z2 = zq; else z3 = zq;
    }
    fft256_reg(z0, z1, z2, z3, buf, lane, tw);
    // windowed time samples: s = 2n, 2n+1 at n = lane+64q; x = conj/1024
    float2 w0 = make_float2(z0.x * h0[0], -z0.y * h1[0]);
    float2 w1 = make_float2(z1.x * h0[1], -z1.y * h1[1]);
    float2 w2 = make_float2(z2.x * h0[2], -z2.y * h1[2]);
    float2 w3 = make_float2(z3.x * h0[3], -z3.y * h1[3]);
    if (j == 0) {
      bp[lane]      = f2h(w0);            // chunk-leading head -> bnd
      bp[lane + 64] = f2h(w1);
    } else {
      float2 v0 = make_float2(pt0.x + w0.x, pt0.y + w0.y);
      float2 v1 = make_float2(pt1.x + w1.x, pt1.y + w1.y);
      outv[obase2 + (size_t)j * 128 + lane] =
          make_float2(fast_tanh(g * v0.x), fast_tanh(g * v0.y));
      outv[obase2 + (size_t)j * 128 + lane + 64] =
          make_float2(fast_tanh(g * v1.x), fast_tanh(g * v1.y));
    }
    pt0 = w2; pt1 = w3;
    wave_sync();
    if (have_next) { C0 = N0; C1 = N1; C2 = N2; C3 = N3; C256 = N256; }
  }
  bp[128 + lane] = f2h(pt0);              // chunk-trailing tail -> bnd
  bp[192 + lane] = f2h(pt1);
}

// ---------------------------------------------------------------------------
// 5) combine boundary chunks: chunk FPB*b <- bnd[b-1].tail + bnd[b].head
// ---------------------------------------------------------------------------
__global__ __launch_bounds__(256) void final_kernel(const __half* __restrict__ bnd,
                                                    const float* __restrict__ gain,
                                                    float* __restrict__ out) {
  int bc = blockIdx.y, b = blockIdx.x;
  int s = threadIdx.x;
  const __half* base = bnd + ((size_t)bc * NBLK) * 2 * HOP;
  float v = __half2float(base[((size_t)b * 2) * HOP + s]);
  if (b > 0) v += __half2float(base[((size_t)(b - 1) * 2 + 1) * HOP + s]);
  float g = gain[bc & (NCH - 1)];
  out[(size_t)bc * T_LEN + (size_t)b * (FPB * HOP) + s] = fast_tanh(g * v);
}

// ---------------------------------------------------------------------------
extern "C" void kernel_launch(void* const* d_in, const int* in_sizes, int n_in,
                              void* d_out, int out_size, void* d_ws, size_t ws_size,
                              hipStream_t stream) {
  (void)in_sizes; (void)n_in; (void)out_size; (void)ws_size;
  const float* x        = (const float*)d_in[0];
  const float* transfer = (const float*)d_in[1];
  const float* mixer    = (const float*)d_in[2];
  const float* gain     = (const float*)d_in[3];
  float* out = (float*)d_out;

  // ws layout (all fp16):
  //  [spec 67,371,008 B][bnd 8,388,608 B][carries 8,421,376 B][y 33,554,432 B]
  char* p = (char*)d_ws;
  __half2* spec    = (__half2*)p;                       p += (size_t)NBC * NFR * NBIN * 4;
  __half2* bnd     = (__half2*)p;                       p += (size_t)NBC * NBLK * 2 * HOP * 2;
  __half2* carries = (__half2*)p;                       p += (size_t)NBC * NBLK * NBIN * 4;
  __half2* y       = (__half2*)p;

  mix_kernel<<<dim3(T_LEN / 512, NBAT), 256, 0, stream>>>(x, mixer, y);
  fft_fwd_kernel<<<dim3(NBC * NBLK / 4), 256, 0, stream>>>(y, transfer, spec);
  carry_kernel<<<dim3((NBC * NBIN + 255) / 256), 256, 0, stream>>>(spec, transfer, carries);
  fft_inv_kernel<<<dim3(NBC * NBLK / 4), 256, 0, stream>>>(spec, carries, transfer, gain, out, (__half2*)bnd);
  final_kernel<<<dim3(NBLK, NBC), 256, 0, stream>>>((const __half*)bnd, gain, out);
}

// Round 10
// 149.447 us; speedup vs baseline: 1.1480x; 1.1480x over previous
//
#include <hip/hip_runtime.h>
#include <hip/hip_fp16.h>
#include <math.h>

// Problem constants
#define T_LEN 131072
#define NCH   32
#define NBAT  4
#define WIN   512
#define HOP   256
#define NFR   512            // frames per (b,c) = T/HOP
#define NBIN  257            // rfft bins
#define NBC   (NBAT*NCH)     // 128
#define FPB   4              // frames per chunk (one wave per chunk)
#define NBLK  (NFR/FPB)      // 128 chunks per bc
#define TWOPI 6.28318530717958647692f

// XOR swizzle for FFT LDS float2 arrays (hits the b64 4-lane/bank floor)
#define SWZ(m) ((m) ^ ((((m) >> 4) & 15)))

__device__ __forceinline__ float2 cmul(float2 u, float2 v) {
  return make_float2(fmaf(u.x, v.x, -u.y * v.y), fmaf(u.x, v.y, u.y * v.x));
}

__device__ __forceinline__ float fast_tanh(float x) {
  float e = __expf(2.0f * x);                    // inf-safe
  return 1.0f - 2.0f * __builtin_amdgcn_rcpf(e + 1.0f);
}

__device__ __forceinline__ float2 h2f(__half2 h) { return __half22float2(h); }
__device__ __forceinline__ __half2 f2h(float2 f) { return __float22half2_rn(f); }

// Wave-level ordering fence: LDS ops of a wave execute in order on the DS
// pipe; this only stops compiler reordering (no s_barrier, no cnt drain).
// Burst global loads are issued BEFORE the first fence so they stay in
// flight across the whole chunk's compute (vmcnt waits only at first use).
__device__ __forceinline__ void wave_sync() {
  asm volatile("" ::: "memory");
  __builtin_amdgcn_wave_barrier();
  asm volatile("" ::: "memory");
}

// radix-4 DIF butterfly
__device__ __forceinline__ void r4bf(float2 a, float2 b, float2 c, float2 d,
                                     float2& y0, float2& t1, float2& t2, float2& t3) {
  float2 apc = make_float2(a.x + c.x, a.y + c.y);
  float2 amc = make_float2(a.x - c.x, a.y - c.y);
  float2 bpd = make_float2(b.x + d.x, b.y + d.y);
  float2 bmd = make_float2(b.x - d.x, b.y - d.y);
  y0 = make_float2(apc.x + bpd.x, apc.y + bpd.y);
  t1 = make_float2(amc.x + bmd.y, amc.y - bmd.x);  // amc - i*bmd
  t2 = make_float2(apc.x - bpd.x, apc.y - bpd.y);
  t3 = make_float2(amc.x - bmd.y, amc.y + bmd.x);  // amc + i*bmd
}

struct TW {
  float2 a1, a2, a3, b1, b2, b3, c1, c2, c3;
};

__device__ __forceinline__ void load_tw(const float2* __restrict__ W256f, int lane, TW& t) {
  t.a1 = W256f[lane];     t.a2 = W256f[2 * lane];  t.a3 = W256f[3 * lane];
  int p1 = 4 * (lane >> 2);
  t.b1 = W256f[p1];       t.b2 = W256f[2 * p1];    t.b3 = W256f[3 * p1];
  int p2 = 16 * (lane >> 4);
  t.c1 = W256f[p2];       t.c2 = W256f[2 * p2];    t.c3 = W256f[3 * p2];
}

// 256-pt forward complex FFT. Input regs z0..z3 = z[lane+64m]; output regs
// z0..z3 = Z[lane+64m]. Stages 0 & 3 in registers; 1 & 2 via wave-private LDS.
__device__ __forceinline__ void fft256_reg(float2& z0, float2& z1, float2& z2, float2& z3,
                                           float2* __restrict__ buf, int lane, const TW& tw) {
  float2 y0, t1, t2, t3;
  // stage 0 (s=1, p=lane): pure register butterfly, scatter 4l..4l+3
  r4bf(z0, z1, z2, z3, y0, t1, t2, t3);
  int o0 = 4 * lane;
  buf[SWZ(o0)]     = y0;
  buf[SWZ(o0 + 1)] = cmul(tw.a1, t1);
  buf[SWZ(o0 + 2)] = cmul(tw.a2, t2);
  buf[SWZ(o0 + 3)] = cmul(tw.a3, t3);
  wave_sync();
  // stage 1 (s=4)
  {
    float2 a = buf[SWZ(lane)], b = buf[SWZ(lane + 64)],
           c = buf[SWZ(lane + 128)], d = buf[SWZ(lane + 192)];
    wave_sync();
    r4bf(a, b, c, d, y0, t1, t2, t3);
    int o = lane + 12 * (lane >> 2);
    buf[SWZ(o)]      = y0;
    buf[SWZ(o + 4)]  = cmul(tw.b1, t1);
    buf[SWZ(o + 8)]  = cmul(tw.b2, t2);
    buf[SWZ(o + 12)] = cmul(tw.b3, t3);
  }
  wave_sync();
  // stage 2 (s=16)
  {
    float2 a = buf[SWZ(lane)], b = buf[SWZ(lane + 64)],
           c = buf[SWZ(lane + 128)], d = buf[SWZ(lane + 192)];
    wave_sync();
    r4bf(a, b, c, d, y0, t1, t2, t3);
    int o = lane + 48 * (lane >> 4);
    buf[SWZ(o)]      = y0;
    buf[SWZ(o + 16)] = cmul(tw.c1, t1);
    buf[SWZ(o + 32)] = cmul(tw.c2, t2);
    buf[SWZ(o + 48)] = cmul(tw.c3, t3);
  }
  wave_sync();
  // stage 3 (s=64, p=0, twiddle-free): outputs land in register layout
  {
    float2 a = buf[SWZ(lane)], b = buf[SWZ(lane + 64)],
           c = buf[SWZ(lane + 128)], d = buf[SWZ(lane + 192)];
    wave_sync();
    r4bf(a, b, c, d, z0, z1, z2, z3);
  }
}

// W256f[m] = exp(-2pi i m/256), m<256 ; W512s[k] = exp(-2pi i k/512), k<=256
__device__ __forceinline__ void build_tables(float2* W256f, float2* W512s) {
  int tid = threadIdx.x;
  float sv, cv;
  __sincosf(-(TWOPI / 256.0f) * (float)tid, &sv, &cv);
  W256f[tid] = make_float2(cv, sv);
  __sincosf(-(TWOPI / 512.0f) * (float)tid, &sv, &cv);
  W512s[tid] = make_float2(cv, sv);
  if (tid == 0) W512s[256] = make_float2(-1.f, 0.f);
}

// ---------------------------------------------------------------------------
// 1) channel mix: y[b,d,t] = sum_c x[b,c,t] * mixer[c,d]   (fp16 output)
// ---------------------------------------------------------------------------
__global__ __launch_bounds__(256) void mix_kernel(const float* __restrict__ x,
                                                  const float* __restrict__ mixer,
                                                  __half2* __restrict__ y) {
  __shared__ float mm[NCH][NCH];
  for (int i = threadIdx.x; i < NCH * NCH; i += 256)
    ((float*)mm)[i] = mixer[i];
  __syncthreads();
  int b = blockIdx.y;
  int t2 = blockIdx.x * 256 + threadIdx.x;     // float2-pair index
  const float2* xv = (const float2*)x;
  float2 xr[NCH];
#pragma unroll
  for (int c = 0; c < NCH; c++)
    xr[c] = xv[(((size_t)(b * NCH + c)) * T_LEN >> 1) + t2];
#pragma unroll 4
  for (int d = 0; d < NCH; d++) {
    float ax = 0.f, ay = 0.f;
#pragma unroll
    for (int c = 0; c < NCH; c++) {
      ax = fmaf(xr[c].x, mm[c][d], ax);
      ay = fmaf(xr[c].y, mm[c][d], ay);
    }
    y[(((size_t)(b * NCH + d)) * T_LEN >> 1) + t2] = f2h(make_float2(ax, ay));
  }
}

// ---------------------------------------------------------------------------
// 2) forward rfft(512) + register-local scan. Wave = one 4-frame chunk.
//    Chunk's y burst-loaded up-front as 10 packed half2 segments (overlapping
//    frame halves share registers). Untangle 0.5s dropped (spec carries 2x).
// ---------------------------------------------------------------------------
__global__ __launch_bounds__(256, 4) void fft_fwd_kernel(const __half2* __restrict__ y,
                                                         const float* __restrict__ transfer,
                                                         __half2* __restrict__ spec) {
  __shared__ float2 fbuf[4][NBIN];       // wave-private FFT/mirror buffer
  __shared__ float2 W256f[256];
  __shared__ float2 W512s[NBIN];
  build_tables(W256f, W512s);
  __syncthreads();
  int wave = threadIdx.x >> 6, lane = threadIdx.x & 63;
  int cid = blockIdx.x * 4 + wave;       // chunk id 0..16383
  int bc = cid >> 7, blk = cid & (NBLK - 1);
  int ch = bc & (NCH - 1);
  float2* buf = fbuf[wave];
  TW tw; load_tw(W256f, lane, tw);
  float cwq[4], swq[4], trq[4];
#pragma unroll
  for (int q = 0; q < 4; q++) {
    int k = lane + 64 * q;
    cwq[q] = W512s[k].x; swq[q] = W512s[k].y;
    trq[q] = transfer[ch * NBIN + k];
  }
  float tr256 = transfer[ch * NBIN + 256];
  float2 s[4] = {make_float2(0,0), make_float2(0,0), make_float2(0,0), make_float2(0,0)};
  float s256x = 0.f;
  size_t base2 = ((size_t)bc * T_LEN + (size_t)blk * (FPB * HOP)) >> 1;  // half2 idx
  size_t fb = ((size_t)bc * NFR + (size_t)blk * FPB) * NBIN;
  bool lastchunk = (blk == NBLK - 1);
  const __half2* src = y + base2;
  // burst-load the chunk: segment p holds samples [128p, 128p+128);
  // frame j uses segments 2j..2j+3. Packed half2 -> 10 VGPRs, all in flight.
  __half2 hz = f2h(make_float2(0.f, 0.f));
  __half2 seg[10];
#pragma unroll
  for (int p = 0; p < 10; p++) {
    seg[p] = (lastchunk && p >= 8) ? hz : src[(size_t)p * 64 + lane];
  }
#pragma unroll
  for (int j = 0; j < FPB; ++j) {
    float2 z0 = h2f(seg[2 * j]);
    float2 z1 = h2f(seg[2 * j + 1]);
    float2 z2 = h2f(seg[2 * j + 2]);
    float2 z3 = h2f(seg[2 * j + 3]);
    fft256_reg(z0, z1, z2, z3, buf, lane, tw);
    // mirror staging
    buf[lane] = z0; buf[lane + 64] = z1; buf[lane + 128] = z2; buf[lane + 192] = z3;
    wave_sync();
    float2 zm0 = buf[(256 - lane) & 255];
    float2 zm1 = buf[192 - lane];
    float2 zm2 = buf[128 - lane];
    float2 zm3 = buf[64 - lane];
    float2 z0b = buf[0];
    wave_sync();
    // untangle (0.5s folded out -> 2x scale) + scan + store, k = lane+64q
#pragma unroll
    for (int q = 0; q < 4; q++) {
      float2 zk  = (q == 0) ? z0 : (q == 1) ? z1 : (q == 2) ? z2 : z3;
      float2 zmk = (q == 0) ? zm0 : (q == 1) ? zm1 : (q == 2) ? zm2 : zm3;
      float Ex = zk.x + zmk.x, Ey = zk.y - zmk.y;
      float dx = zk.x - zmk.x, dy = zk.y + zmk.y;
      float Ox = dy, Oy = -dx;
      float Yx = Ex + Ox * cwq[q] - Oy * swq[q];
      float Yy = Ey + Ox * swq[q] + Oy * cwq[q];
      s[q].x = trq[q] * (Yx + s[q].x);
      s[q].y = trq[q] * (Yy + s[q].y);
      spec[fb + (size_t)j * NBIN + lane + 64 * q] = f2h(s[q]);
    }
    // bin 256 (2x scale to match): Y = 2*(Z0.x - Z0.y)
    s256x = tr256 * (2.0f * (z0b.x - z0b.y) + s256x);
    if (lane == 0) spec[fb + (size_t)j * NBIN + 256] = f2h(make_float2(s256x, 0.f));
    wave_sync();
  }
}

// ---------------------------------------------------------------------------
// 3) carry scan across chunks: C[0]=0; C[i] = final[i-1] + tr^FPB * C[i-1]
// ---------------------------------------------------------------------------
__global__ __launch_bounds__(256) void carry_kernel(const __half2* __restrict__ spec,
                                                    const float* __restrict__ transfer,
                                                    __half2* __restrict__ carries) {
  int tid = blockIdx.x * 256 + threadIdx.x;
  if (tid >= NBC * NBIN) return;
  int bc = tid / NBIN, k = tid - bc * NBIN;
  int ch = bc & (NCH - 1);
  float tr = transfer[ch * NBIN + k];
  float tr2 = tr * tr;
  float tr4 = tr2 * tr2;          // tr^FPB
  const __half2* fin = spec + (size_t)bc * NFR * NBIN + (size_t)(FPB - 1) * NBIN + k;
  __half2* cp = carries + (size_t)bc * NBLK * NBIN + k;
  float cx = 0.f, cy = 0.f;
  for (int i = 0; i < NBLK; i += 16) {
    float2 v[16];
#pragma unroll
    for (int u = 0; u < 16; u++) v[u] = h2f(fin[(size_t)(i + u) * FPB * NBIN]);
#pragma unroll
    for (int u = 0; u < 16; u++) {
      cp[(size_t)(i + u) * NBIN] = f2h(make_float2(cx, cy));
      cx = v[u].x + tr4 * cx;
      cy = v[u].y + tr4 * cy;
    }
  }
}

// ---------------------------------------------------------------------------
// 4) inverse rfft + hann + register OLA. Wave = one 4-frame chunk.
//    Chunk's spec burst-loaded up-front as 20 packed half2 regs.
//    Untangle 0.5s dropped; total 4x scale absorbed into hann (1/1024).
// ---------------------------------------------------------------------------
__global__ __launch_bounds__(256, 4) void fft_inv_kernel(const __half2* __restrict__ spec,
                                                         const __half2* __restrict__ carries,
                                                         const float* __restrict__ transfer,
                                                         const float* __restrict__ gain,
                                                         float* __restrict__ out,
                                                         __half2* __restrict__ bnd) {
  __shared__ float2 fbuf[4][NBIN];
  __shared__ float2 W256f[256];
  __shared__ float2 W512s[NBIN];
  build_tables(W256f, W512s);
  __syncthreads();
  int wave = threadIdx.x >> 6, lane = threadIdx.x & 63;
  int cid = blockIdx.x * 4 + wave;
  int bc = cid >> 7, blk = cid & (NBLK - 1);
  int ch = bc & (NCH - 1);
  float2* buf = fbuf[wave];
  TW tw; load_tw(W256f, lane, tw);
  const __half2* crp = carries + ((size_t)bc * NBLK + blk) * NBIN;
  const __half2* sp0 = spec + ((size_t)bc * NFR + (size_t)blk * FPB) * NBIN;
  // burst-load the chunk's spectra: 4 frames x (4 + bin256) packed half2.
  __half2 S[FPB][4];
  __half2 S256[FPB];
#pragma unroll
  for (int j = 0; j < FPB; j++) {
#pragma unroll
    for (int q = 0; q < 4; q++) S[j][q] = sp0[(size_t)j * NBIN + lane + 64 * q];
    S256[j] = sp0[(size_t)j * NBIN + 256];
  }
  float cwq[4], swq[4], trq[4], trp[4], h0[4], h1[4];
  float2 cv[4];
#pragma unroll
  for (int q = 0; q < 4; q++) {
    int k = lane + 64 * q;
    cwq[q] = W512s[k].x; swq[q] = -W512s[k].y;   // exp(+2pi i k/512)
    trq[q] = transfer[ch * NBIN + k];
    trp[q] = trq[q];
    cv[q] = h2f(crp[k]);
    int t0 = 2 * k, t1 = 2 * k + 1;
    int i0 = (t0 <= 256) ? t0 : 512 - t0;
    int i1 = (t1 <= 256) ? t1 : 512 - t1;
    h0[q] = (0.5f - 0.5f * W512s[i0].x) * (1.0f / 1024.0f);   // 1/256 and 1/4 scale
    h1[q] = (0.5f - 0.5f * W512s[i1].x) * (1.0f / 1024.0f);
  }
  float tr256 = transfer[ch * NBIN + 256], trp256 = tr256;
  float2 cv256 = h2f(crp[256]);
  float g = gain[ch];
  float2* outv = (float2*)out;
  size_t obase2 = ((size_t)bc * T_LEN + (size_t)blk * (FPB * HOP)) >> 1;
  __half2* bp = bnd + (((size_t)bc * NBLK + blk) * 2) * (HOP / 2);
  float2 pt0, pt1;                        // previous frame's windowed tail
#pragma unroll
  for (int j = 0; j < FPB; ++j) {
    // carry fix-up: O = local + tr^(j+1) * carry
    float2 Y0 = h2f(S[j][0]); Y0.x = fmaf(trp[0], cv[0].x, Y0.x); Y0.y = fmaf(trp[0], cv[0].y, Y0.y);
    float2 Y1 = h2f(S[j][1]); Y1.x = fmaf(trp[1], cv[1].x, Y1.x); Y1.y = fmaf(trp[1], cv[1].y, Y1.y);
    float2 Y2 = h2f(S[j][2]); Y2.x = fmaf(trp[2], cv[2].x, Y2.x); Y2.y = fmaf(trp[2], cv[2].y, Y2.y);
    float2 Y3 = h2f(S[j][3]); Y3.x = fmaf(trp[3], cv[3].x, Y3.x); Y3.y = fmaf(trp[3], cv[3].y, Y3.y);
    float2 y256 = h2f(S256[j]);
    y256.x = fmaf(trp256, cv256.x, y256.x);
    y256.y = fmaf(trp256, cv256.y, y256.y);
#pragma unroll
    for (int q = 0; q < 4; q++) trp[q] *= trq[q];
    trp256 *= tr256;
    // mirror staging
    buf[lane] = Y0; buf[lane + 64] = Y1; buf[lane + 128] = Y2; buf[lane + 192] = Y3;
    if (lane == 0) buf[256] = y256;
    wave_sync();
    float2 ym0 = buf[256 - lane];
    float2 ym1 = buf[192 - lane];
    float2 ym2 = buf[128 - lane];
    float2 ym3 = buf[64 - lane];
    wave_sync();
    // inverse untangle (0.5s folded into h) -> conj'd FFT input
    float2 z0, z1, z2, z3;
#pragma unroll
    for (int q = 0; q < 4; q++) {
      float2 yk  = (q == 0) ? Y0 : (q == 1) ? Y1 : (q == 2) ? Y2 : Y3;
      float2 ymk = (q == 0) ? ym0 : (q == 1) ? ym1 : (q == 2) ? ym2 : ym3;
      float Ex = yk.x + ymk.x, Ey = yk.y - ymk.y;
      float dx = yk.x - ymk.x, dy = yk.y + ymk.y;
      float Ox = dx * cwq[q] - dy * swq[q];
      float Oy = dx * swq[q] + dy * cwq[q];
      float2 zq = make_float2(Ex - Oy, -(Ey + Ox));
      if (q == 0) z0 = zq; else if (q == 1) z1 = zq; else if (q == 2) z2 = zq; else z3 = zq;
    }
    fft256_reg(z0, z1, z2, z3, buf, lane, tw);
    // windowed time samples: s = 2n, 2n+1 at n = lane+64q; x = conj/1024
    float2 w0 = make_float2(z0.x * h0[0], -z0.y * h1[0]);
    float2 w1 = make_float2(z1.x * h0[1], -z1.y * h1[1]);
    float2 w2 = make_float2(z2.x * h0[2], -z2.y * h1[2]);
    float2 w3 = make_float2(z3.x * h0[3], -z3.y * h1[3]);
    if (j == 0) {
      bp[lane]      = f2h(w0);            // chunk-leading head -> bnd
      bp[lane + 64] = f2h(w1);
    } else {
      float2 v0 = make_float2(pt0.x + w0.x, pt0.y + w0.y);
      float2 v1 = make_float2(pt1.x + w1.x, pt1.y + w1.y);
      outv[obase2 + (size_t)j * 128 + lane] =
          make_float2(fast_tanh(g * v0.x), fast_tanh(g * v0.y));
      outv[obase2 + (size_t)j * 128 + lane + 64] =
          make_float2(fast_tanh(g * v1.x), fast_tanh(g * v1.y));
    }
    pt0 = w2; pt1 = w3;
    wave_sync();
  }
  bp[128 + lane] = f2h(pt0);              // chunk-trailing tail -> bnd
  bp[192 + lane] = f2h(pt1);
}

// ---------------------------------------------------------------------------
// 5) combine boundary chunks: chunk FPB*b <- bnd[b-1].tail + bnd[b].head
// ---------------------------------------------------------------------------
__global__ __launch_bounds__(256) void final_kernel(const __half* __restrict__ bnd,
                                                    const float* __restrict__ gain,
                                                    float* __restrict__ out) {
  int bc = blockIdx.y, b = blockIdx.x;
  int s = threadIdx.x;
  const __half* base = bnd + ((size_t)bc * NBLK) * 2 * HOP;
  float v = __half2float(base[((size_t)b * 2) * HOP + s]);
  if (b > 0) v += __half2float(base[((size_t)(b - 1) * 2 + 1) * HOP + s]);
  float g = gain[bc & (NCH - 1)];
  out[(size_t)bc * T_LEN + (size_t)b * (FPB * HOP) + s] = fast_tanh(g * v);
}

// ---------------------------------------------------------------------------
extern "C" void kernel_launch(void* const* d_in, const int* in_sizes, int n_in,
                              void* d_out, int out_size, void* d_ws, size_t ws_size,
                              hipStream_t stream) {
  (void)in_sizes; (void)n_in; (void)out_size; (void)ws_size;
  const float* x        = (const float*)d_in[0];
  const float* transfer = (const float*)d_in[1];
  const float* mixer    = (const float*)d_in[2];
  const float* gain     = (const float*)d_in[3];
  float* out = (float*)d_out;

  // ws layout (all fp16):
  //  [spec 67,371,008 B][bnd 16,777,216 B][carries 16,842,752 B][y 33,554,432 B]
  char* p = (char*)d_ws;
  __half2* spec    = (__half2*)p;                       p += (size_t)NBC * NFR * NBIN * 4;
  __half2* bnd     = (__half2*)p;                       p += (size_t)NBC * NBLK * 2 * HOP * 2;
  __half2* carries = (__half2*)p;                       p += (size_t)NBC * NBLK * NBIN * 4;
  __half2* y       = (__half2*)p;

  mix_kernel<<<dim3(T_LEN / 512, NBAT), 256, 0, stream>>>(x, mixer, y);
  fft_fwd_kernel<<<dim3(NBC * NBLK / 4), 256, 0, stream>>>(y, transfer, spec);
  carry_kernel<<<dim3((NBC * NBIN + 255) / 256), 256, 0, stream>>>(spec, transfer, carries);
  fft_inv_kernel<<<dim3(NBC * NBLK / 4), 256, 0, stream>>>(spec, carries, transfer, gain, out, (__half2*)bnd);
  final_kernel<<<dim3(NBLK, NBC), 256, 0, stream>>>((const __half*)bnd, gain, out);
}

// Round 11
// 148.814 us; speedup vs baseline: 1.1529x; 1.0042x over previous
//
#include <hip/hip_runtime.h>
#include <hip/hip_fp16.h>
#include <math.h>

// Problem constants
#define T_LEN 131072
#define NCH   32
#define NBAT  4
#define WIN   512
#define HOP   256
#define NFR   512            // frames per (b,c) = T/HOP
#define NBIN  257            // rfft bins
#define NBC   (NBAT*NCH)     // 128
#define FPB   4              // frames per chunk (one wave per chunk)
#define NBLK  (NFR/FPB)      // 128 chunks per bc
#define TWOPI 6.28318530717958647692f

// XOR swizzle for FFT LDS float2 arrays (hits the b64 4-lane/bank floor)
#define SWZ(m) ((m) ^ ((((m) >> 4) & 15)))

__device__ __forceinline__ float2 cmul(float2 u, float2 v) {
  return make_float2(fmaf(u.x, v.x, -u.y * v.y), fmaf(u.x, v.y, u.y * v.x));
}

__device__ __forceinline__ float fast_tanh(float x) {
  float e = __expf(2.0f * x);                    // inf-safe
  return 1.0f - 2.0f * __builtin_amdgcn_rcpf(e + 1.0f);
}

__device__ __forceinline__ float2 h2f(__half2 h) { return __half22float2(h); }
__device__ __forceinline__ __half2 f2h(float2 f) { return __float22half2_rn(f); }

// Cross-lane pull via the LDS crossbar (no LDS storage, no fences needed).
__device__ __forceinline__ float2 bperm2(int addr, float2 v) {
  int vx = __builtin_amdgcn_ds_bpermute(addr, __float_as_int(v.x));
  int vy = __builtin_amdgcn_ds_bpermute(addr, __float_as_int(v.y));
  return make_float2(__int_as_float(vx), __int_as_float(vy));
}

// Wave-level ordering fence: LDS ops of a wave execute in order on the DS
// pipe; this only stops compiler reordering (no s_barrier, no cnt drain).
__device__ __forceinline__ void wave_sync() {
  asm volatile("" ::: "memory");
  __builtin_amdgcn_wave_barrier();
  asm volatile("" ::: "memory");
}

// radix-4 DIF butterfly
__device__ __forceinline__ void r4bf(float2 a, float2 b, float2 c, float2 d,
                                     float2& y0, float2& t1, float2& t2, float2& t3) {
  float2 apc = make_float2(a.x + c.x, a.y + c.y);
  float2 amc = make_float2(a.x - c.x, a.y - c.y);
  float2 bpd = make_float2(b.x + d.x, b.y + d.y);
  float2 bmd = make_float2(b.x - d.x, b.y - d.y);
  y0 = make_float2(apc.x + bpd.x, apc.y + bpd.y);
  t1 = make_float2(amc.x + bmd.y, amc.y - bmd.x);  // amc - i*bmd
  t2 = make_float2(apc.x - bpd.x, apc.y - bpd.y);
  t3 = make_float2(amc.x - bmd.y, amc.y + bmd.x);  // amc + i*bmd
}

struct TW {
  float2 a1, a2, a3, b1, b2, b3, c1, c2, c3;
};

__device__ __forceinline__ void load_tw(const float2* __restrict__ W256f, int lane, TW& t) {
  t.a1 = W256f[lane];     t.a2 = W256f[2 * lane];  t.a3 = W256f[3 * lane];
  int p1 = 4 * (lane >> 2);
  t.b1 = W256f[p1];       t.b2 = W256f[2 * p1];    t.b3 = W256f[3 * p1];
  int p2 = 16 * (lane >> 4);
  t.c1 = W256f[p2];       t.c2 = W256f[2 * p2];    t.c3 = W256f[3 * p2];
}

// 256-pt forward complex FFT. Input regs z0..z3 = z[lane+64m]; output regs
// z0..z3 = Z[lane+64m]. Stages 0 & 3 in registers; 1 & 2 via wave-private LDS.
__device__ __forceinline__ void fft256_reg(float2& z0, float2& z1, float2& z2, float2& z3,
                                           float2* __restrict__ buf, int lane, const TW& tw) {
  float2 y0, t1, t2, t3;
  // stage 0 (s=1, p=lane): pure register butterfly, scatter 4l..4l+3
  r4bf(z0, z1, z2, z3, y0, t1, t2, t3);
  int o0 = 4 * lane;
  buf[SWZ(o0)]     = y0;
  buf[SWZ(o0 + 1)] = cmul(tw.a1, t1);
  buf[SWZ(o0 + 2)] = cmul(tw.a2, t2);
  buf[SWZ(o0 + 3)] = cmul(tw.a3, t3);
  wave_sync();
  // stage 1 (s=4)
  {
    float2 a = buf[SWZ(lane)], b = buf[SWZ(lane + 64)],
           c = buf[SWZ(lane + 128)], d = buf[SWZ(lane + 192)];
    wave_sync();
    r4bf(a, b, c, d, y0, t1, t2, t3);
    int o = lane + 12 * (lane >> 2);
    buf[SWZ(o)]      = y0;
    buf[SWZ(o + 4)]  = cmul(tw.b1, t1);
    buf[SWZ(o + 8)]  = cmul(tw.b2, t2);
    buf[SWZ(o + 12)] = cmul(tw.b3, t3);
  }
  wave_sync();
  // stage 2 (s=16)
  {
    float2 a = buf[SWZ(lane)], b = buf[SWZ(lane + 64)],
           c = buf[SWZ(lane + 128)], d = buf[SWZ(lane + 192)];
    wave_sync();
    r4bf(a, b, c, d, y0, t1, t2, t3);
    int o = lane + 48 * (lane >> 4);
    buf[SWZ(o)]      = y0;
    buf[SWZ(o + 16)] = cmul(tw.c1, t1);
    buf[SWZ(o + 32)] = cmul(tw.c2, t2);
    buf[SWZ(o + 48)] = cmul(tw.c3, t3);
  }
  wave_sync();
  // stage 3 (s=64, p=0, twiddle-free): outputs land in register layout
  {
    float2 a = buf[SWZ(lane)], b = buf[SWZ(lane + 64)],
           c = buf[SWZ(lane + 128)], d = buf[SWZ(lane + 192)];
    wave_sync();
    r4bf(a, b, c, d, z0, z1, z2, z3);
  }
}

// W256f[m] = exp(-2pi i m/256), m<256 ; W512s[k] = exp(-2pi i k/512), k<=256
__device__ __forceinline__ void build_tables(float2* W256f, float2* W512s) {
  int tid = threadIdx.x;
  float sv, cv;
  __sincosf(-(TWOPI / 256.0f) * (float)tid, &sv, &cv);
  W256f[tid] = make_float2(cv, sv);
  __sincosf(-(TWOPI / 512.0f) * (float)tid, &sv, &cv);
  W512s[tid] = make_float2(cv, sv);
  if (tid == 0) W512s[256] = make_float2(-1.f, 0.f);
}

// ---------------------------------------------------------------------------
// 1) channel mix: y[b,d,t] = sum_c x[b,c,t] * mixer[c,d]   (fp16 output)
// ---------------------------------------------------------------------------
__global__ __launch_bounds__(256) void mix_kernel(const float* __restrict__ x,
                                                  const float* __restrict__ mixer,
                                                  __half2* __restrict__ y) {
  __shared__ float mm[NCH][NCH];
  for (int i = threadIdx.x; i < NCH * NCH; i += 256)
    ((float*)mm)[i] = mixer[i];
  __syncthreads();
  int b = blockIdx.y;
  int t2 = blockIdx.x * 256 + threadIdx.x;     // float2-pair index
  const float2* xv = (const float2*)x;
  float2 xr[NCH];
#pragma unroll
  for (int c = 0; c < NCH; c++)
    xr[c] = xv[(((size_t)(b * NCH + c)) * T_LEN >> 1) + t2];
#pragma unroll 4
  for (int d = 0; d < NCH; d++) {
    float ax = 0.f, ay = 0.f;
#pragma unroll
    for (int c = 0; c < NCH; c++) {
      ax = fmaf(xr[c].x, mm[c][d], ax);
      ay = fmaf(xr[c].y, mm[c][d], ay);
    }
    y[(((size_t)(b * NCH + d)) * T_LEN >> 1) + t2] = f2h(make_float2(ax, ay));
  }
}

// ---------------------------------------------------------------------------
// 2) forward rfft(512) + register-local scan. Wave = one 4-frame chunk.
//    Chunk burst-loaded as 10 packed half2 segments (overlap shared).
//    Mirror exchange via ds_bpermute (no LDS staging). Untangle 0.5s dropped
//    (spec carries a uniform 2x scale, absorbed in inv's hann).
// ---------------------------------------------------------------------------
__global__ __launch_bounds__(256, 4) void fft_fwd_kernel(const __half2* __restrict__ y,
                                                         const float* __restrict__ transfer,
                                                         __half2* __restrict__ spec) {
  __shared__ float2 fbuf[4][256];        // wave-private FFT buffer
  __shared__ float2 W256f[256];
  __shared__ float2 W512s[NBIN];
  build_tables(W256f, W512s);
  __syncthreads();
  int wave = threadIdx.x >> 6, lane = threadIdx.x & 63;
  int cid = blockIdx.x * 4 + wave;       // chunk id 0..16383
  int bc = cid >> 7, blk = cid & (NBLK - 1);
  int ch = bc & (NCH - 1);
  float2* buf = fbuf[wave];
  TW tw; load_tw(W256f, lane, tw);
  float cwq[4], swq[4], trq[4];
#pragma unroll
  for (int q = 0; q < 4; q++) {
    int k = lane + 64 * q;
    cwq[q] = W512s[k].x; swq[q] = W512s[k].y;
    trq[q] = transfer[ch * NBIN + k];
  }
  float tr256 = transfer[ch * NBIN + 256];
  float2 s[4] = {make_float2(0,0), make_float2(0,0), make_float2(0,0), make_float2(0,0)};
  float s256x = 0.f;
  size_t base2 = ((size_t)bc * T_LEN + (size_t)blk * (FPB * HOP)) >> 1;  // half2 idx
  size_t fb = ((size_t)bc * NFR + (size_t)blk * FPB) * NBIN;
  bool lastchunk = (blk == NBLK - 1);
  const __half2* src = y + base2;
  // burst-load the chunk: segment p holds samples [128p, 128p+128);
  // frame j uses segments 2j..2j+3. Packed half2 -> 10 VGPRs, all in flight.
  __half2 hz = f2h(make_float2(0.f, 0.f));
  __half2 seg[10];
#pragma unroll
  for (int p = 0; p < 10; p++) {
    seg[p] = (lastchunk && p >= 8) ? hz : src[(size_t)p * 64 + lane];
  }
  int maddr = ((64 - lane) & 63) << 2;   // bpermute byte addr: lane 64-l
#pragma unroll
  for (int j = 0; j < FPB; ++j) {
    float2 z0 = h2f(seg[2 * j]);
    float2 z1 = h2f(seg[2 * j + 1]);
    float2 z2 = h2f(seg[2 * j + 2]);
    float2 z3 = h2f(seg[2 * j + 3]);
    fft256_reg(z0, z1, z2, z3, buf, lane, tw);
    // mirror via crossbar: zm[q] = Z[256-k], k = lane+64q
    float2 zm0 = bperm2(maddr, z3);
    float2 zm1 = bperm2(maddr, z2);
    float2 zm2 = bperm2(maddr, z1);
    float2 zm3 = bperm2(maddr, z0);
    if (lane == 0) { zm0 = z0; zm1 = z3; zm2 = z2; zm3 = z1; }
    // untangle (0.5s folded out -> 2x scale) + scan + store, k = lane+64q
#pragma unroll
    for (int q = 0; q < 4; q++) {
      float2 zk  = (q == 0) ? z0 : (q == 1) ? z1 : (q == 2) ? z2 : z3;
      float2 zmk = (q == 0) ? zm0 : (q == 1) ? zm1 : (q == 2) ? zm2 : zm3;
      float Ex = zk.x + zmk.x, Ey = zk.y - zmk.y;
      float dx = zk.x - zmk.x, dy = zk.y + zmk.y;
      float Ox = dy, Oy = -dx;
      float Yx = Ex + Ox * cwq[q] - Oy * swq[q];
      float Yy = Ey + Ox * swq[q] + Oy * cwq[q];
      s[q].x = trq[q] * (Yx + s[q].x);
      s[q].y = trq[q] * (Yy + s[q].y);
      spec[fb + (size_t)j * NBIN + lane + 64 * q] = f2h(s[q]);
    }
    // bin 256 (2x scale): Y = 2*(Z[0].x - Z[0].y); lane 0 owns Z[0] = z0
    s256x = tr256 * (2.0f * (z0.x - z0.y) + s256x);
    if (lane == 0) spec[fb + (size_t)j * NBIN + 256] = f2h(make_float2(s256x, 0.f));
    wave_sync();                         // next frame's stage-0 writes wait
  }
}

// ---------------------------------------------------------------------------
// 3) carry scan across chunks: C[0]=0; C[i] = final[i-1] + tr^FPB * C[i-1]
// ---------------------------------------------------------------------------
__global__ __launch_bounds__(256) void carry_kernel(const __half2* __restrict__ spec,
                                                    const float* __restrict__ transfer,
                                                    __half2* __restrict__ carries) {
  int tid = blockIdx.x * 256 + threadIdx.x;
  if (tid >= NBC * NBIN) return;
  int bc = tid / NBIN, k = tid - bc * NBIN;
  int ch = bc & (NCH - 1);
  float tr = transfer[ch * NBIN + k];
  float tr2 = tr * tr;
  float tr4 = tr2 * tr2;          // tr^FPB
  const __half2* fin = spec + (size_t)bc * NFR * NBIN + (size_t)(FPB - 1) * NBIN + k;
  __half2* cp = carries + (size_t)bc * NBLK * NBIN + k;
  float cx = 0.f, cy = 0.f;
  for (int i = 0; i < NBLK; i += 16) {
    float2 v[16];
#pragma unroll
    for (int u = 0; u < 16; u++) v[u] = h2f(fin[(size_t)(i + u) * FPB * NBIN]);
#pragma unroll
    for (int u = 0; u < 16; u++) {
      cp[(size_t)(i + u) * NBIN] = f2h(make_float2(cx, cy));
      cx = v[u].x + tr4 * cx;
      cy = v[u].y + tr4 * cy;
    }
  }
}

// ---------------------------------------------------------------------------
// 4) inverse rfft + hann + register OLA. Wave = one 4-frame chunk.
//    Per-frame spec loads (no burst — R9's burst spilled). Mirror via
//    ds_bpermute. Untangle 0.5s dropped; total 4x folded into hann (1/1024).
// ---------------------------------------------------------------------------
__global__ __launch_bounds__(256, 4) void fft_inv_kernel(const __half2* __restrict__ spec,
                                                         const __half2* __restrict__ carries,
                                                         const float* __restrict__ transfer,
                                                         const float* __restrict__ gain,
                                                         float* __restrict__ out,
                                                         __half2* __restrict__ bnd) {
  __shared__ float2 fbuf[4][256];
  __shared__ float2 W256f[256];
  __shared__ float2 W512s[NBIN];
  build_tables(W256f, W512s);
  __syncthreads();
  int wave = threadIdx.x >> 6, lane = threadIdx.x & 63;
  int cid = blockIdx.x * 4 + wave;
  int bc = cid >> 7, blk = cid & (NBLK - 1);
  int ch = bc & (NCH - 1);
  float2* buf = fbuf[wave];
  TW tw; load_tw(W256f, lane, tw);
  const __half2* crp = carries + ((size_t)bc * NBLK + blk) * NBIN;
  float cwq[4], swq[4], trq[4], trp[4], h0[4], h1[4];
  float2 cv[4];
#pragma unroll
  for (int q = 0; q < 4; q++) {
    int k = lane + 64 * q;
    cwq[q] = W512s[k].x; swq[q] = -W512s[k].y;   // exp(+2pi i k/512)
    trq[q] = transfer[ch * NBIN + k];
    trp[q] = trq[q];
    cv[q] = h2f(crp[k]);
    int t0 = 2 * k, t1 = 2 * k + 1;
    int i0 = (t0 <= 256) ? t0 : 512 - t0;
    int i1 = (t1 <= 256) ? t1 : 512 - t1;
    h0[q] = (0.5f - 0.5f * W512s[i0].x) * (1.0f / 1024.0f);   // 1/256 and 1/4 scale
    h1[q] = (0.5f - 0.5f * W512s[i1].x) * (1.0f / 1024.0f);
  }
  float tr256 = transfer[ch * NBIN + 256], trp256 = tr256;
  float2 cv256 = h2f(crp[256]);
  float g = gain[ch];
  const __half2* sp0 = spec + ((size_t)bc * NFR + (size_t)blk * FPB) * NBIN;
  float2* outv = (float2*)out;
  size_t obase2 = ((size_t)bc * T_LEN + (size_t)blk * (FPB * HOP)) >> 1;
  __half2* bp = bnd + (((size_t)bc * NBLK + blk) * 2) * (HOP / 2);
  int maddr = ((64 - lane) & 63) << 2;   // bpermute byte addr: lane 64-l
  float2 pt0, pt1;                        // previous frame's windowed tail
#pragma unroll
  for (int j = 0; j < FPB; ++j) {
    const __half2* sp = sp0 + (size_t)j * NBIN;
    // load + carry fix-up: O = local + tr^(j+1) * carry
    float2 Y0 = h2f(sp[lane]);       Y0.x = fmaf(trp[0], cv[0].x, Y0.x); Y0.y = fmaf(trp[0], cv[0].y, Y0.y);
    float2 Y1 = h2f(sp[lane + 64]);  Y1.x = fmaf(trp[1], cv[1].x, Y1.x); Y1.y = fmaf(trp[1], cv[1].y, Y1.y);
    float2 Y2 = h2f(sp[lane + 128]); Y2.x = fmaf(trp[2], cv[2].x, Y2.x); Y2.y = fmaf(trp[2], cv[2].y, Y2.y);
    float2 Y3 = h2f(sp[lane + 192]); Y3.x = fmaf(trp[3], cv[3].x, Y3.x); Y3.y = fmaf(trp[3], cv[3].y, Y3.y);
    float2 y256 = h2f(sp[256]);      // lane-uniform load
    y256.x = fmaf(trp256, cv256.x, y256.x);
    y256.y = fmaf(trp256, cv256.y, y256.y);
#pragma unroll
    for (int q = 0; q < 4; q++) trp[q] *= trq[q];
    trp256 *= tr256;
    // mirror via crossbar: ym[q] = Y[256-k]; lane 0 fixups from own regs
    float2 ym0 = bperm2(maddr, Y3);
    float2 ym1 = bperm2(maddr, Y2);
    float2 ym2 = bperm2(maddr, Y1);
    float2 ym3 = bperm2(maddr, Y0);
    if (lane == 0) { ym0 = y256; ym1 = Y3; ym2 = Y2; ym3 = Y1; }
    // inverse untangle (0.5s folded into h) -> conj'd FFT input
    float2 z0, z1, z2, z3;
#pragma unroll
    for (int q = 0; q < 4; q++) {
      float2 yk  = (q == 0) ? Y0 : (q == 1) ? Y1 : (q == 2) ? Y2 : Y3;
      float2 ymk = (q == 0) ? ym0 : (q == 1) ? ym1 : (q == 2) ? ym2 : ym3;
      float Ex = yk.x + ymk.x, Ey = yk.y - ymk.y;
      float dx = yk.x - ymk.x, dy = yk.y + ymk.y;
      float Ox = dx * cwq[q] - dy * swq[q];
      float Oy = dx * swq[q] + dy * cwq[q];
      float2 zq = make_float2(Ex - Oy, -(Ey + Ox));
      if (q == 0) z0 = zq; else if (q == 1) z1 = zq; else if (q == 2) z2 = zq; else z3 = zq;
    }
    fft256_reg(z0, z1, z2, z3, buf, lane, tw);
    // windowed time samples: s = 2n, 2n+1 at n = lane+64q; x = conj/1024
    float2 w0 = make_float2(z0.x * h0[0], -z0.y * h1[0]);
    float2 w1 = make_float2(z1.x * h0[1], -z1.y * h1[1]);
    float2 w2 = make_float2(z2.x * h0[2], -z2.y * h1[2]);
    float2 w3 = make_float2(z3.x * h0[3], -z3.y * h1[3]);
    if (j == 0) {
      bp[lane]      = f2h(w0);            // chunk-leading head -> bnd
      bp[lane + 64] = f2h(w1);
    } else {
      float2 v0 = make_float2(pt0.x + w0.x, pt0.y + w0.y);
      float2 v1 = make_float2(pt1.x + w1.x, pt1.y + w1.y);
      outv[obase2 + (size_t)j * 128 + lane] =
          make_float2(fast_tanh(g * v0.x), fast_tanh(g * v0.y));
      outv[obase2 + (size_t)j * 128 + lane + 64] =
          make_float2(fast_tanh(g * v1.x), fast_tanh(g * v1.y));
    }
    pt0 = w2; pt1 = w3;
    wave_sync();                         // next frame's stage-0 writes wait
  }
  bp[128 + lane] = f2h(pt0);              // chunk-trailing tail -> bnd
  bp[192 + lane] = f2h(pt1);
}

// ---------------------------------------------------------------------------
// 5) combine boundary chunks: chunk FPB*b <- bnd[b-1].tail + bnd[b].head
// ---------------------------------------------------------------------------
__global__ __launch_bounds__(256) void final_kernel(const __half* __restrict__ bnd,
                                                    const float* __restrict__ gain,
                                                    float* __restrict__ out) {
  int bc = blockIdx.y, b = blockIdx.x;
  int s = threadIdx.x;
  const __half* base = bnd + ((size_t)bc * NBLK) * 2 * HOP;
  float v = __half2float(base[((size_t)b * 2) * HOP + s]);
  if (b > 0) v += __half2float(base[((size_t)(b - 1) * 2 + 1) * HOP + s]);
  float g = gain[bc & (NCH - 1)];
  out[(size_t)bc * T_LEN + (size_t)b * (FPB * HOP) + s] = fast_tanh(g * v);
}

// ---------------------------------------------------------------------------
extern "C" void kernel_launch(void* const* d_in, const int* in_sizes, int n_in,
                              void* d_out, int out_size, void* d_ws, size_t ws_size,
                              hipStream_t stream) {
  (void)in_sizes; (void)n_in; (void)out_size; (void)ws_size;
  const float* x        = (const float*)d_in[0];
  const float* transfer = (const float*)d_in[1];
  const float* mixer    = (const float*)d_in[2];
  const float* gain     = (const float*)d_in[3];
  float* out = (float*)d_out;

  // ws layout (all fp16):
  //  [spec 67,371,008 B][bnd 16,777,216 B][carries 16,842,752 B][y 33,554,432 B]
  char* p = (char*)d_ws;
  __half2* spec    = (__half2*)p;                       p += (size_t)NBC * NFR * NBIN * 4;
  __half2* bnd     = (__half2*)p;                       p += (size_t)NBC * NBLK * 2 * HOP * 2;
  __half2* carries = (__half2*)p;                       p += (size_t)NBC * NBLK * NBIN * 4;
  __half2* y       = (__half2*)p;

  mix_kernel<<<dim3(T_LEN / 512, NBAT), 256, 0, stream>>>(x, mixer, y);
  fft_fwd_kernel<<<dim3(NBC * NBLK / 4), 256, 0, stream>>>(y, transfer, spec);
  carry_kernel<<<dim3((NBC * NBIN + 255) / 256), 256, 0, stream>>>(spec, transfer, carries);
  fft_inv_kernel<<<dim3(NBC * NBLK / 4), 256, 0, stream>>>(spec, carries, transfer, gain, out, (__half2*)bnd);
  final_kernel<<<dim3(NBLK, NBC), 256, 0, stream>>>((const __half*)bnd, gain, out);
}

// Round 12
// 120.202 us; speedup vs baseline: 1.4273x; 1.2380x over previous
//
#include <hip/hip_runtime.h>
#include <hip/hip_fp16.h>
#include <math.h>

// Problem constants
#define T_LEN 131072
#define NCH   32
#define NBAT  4
#define WIN   512
#define HOP   256
#define NFR   512            // frames per (b,c) = T/HOP
#define NBIN  257            // rfft bins
#define NBC   (NBAT*NCH)     // 128
#define FPB   4              // frames per chunk (one wave per chunk)
#define NBLK  (NFR/FPB)      // 128 chunks per bc
#define TWOPI 6.28318530717958647692f

// XOR swizzle for FFT LDS float2 arrays (hits the b64 4-lane/bank floor)
#define SWZ(m) ((m) ^ ((((m) >> 4) & 15)))

__device__ __forceinline__ float2 cmul(float2 u, float2 v) {
  return make_float2(fmaf(u.x, v.x, -u.y * v.y), fmaf(u.x, v.y, u.y * v.x));
}

__device__ __forceinline__ float fast_tanh(float x) {
  float e = __expf(2.0f * x);                    // inf-safe
  return 1.0f - 2.0f * __builtin_amdgcn_rcpf(e + 1.0f);
}

__device__ __forceinline__ float2 h2f(__half2 h) { return __half22float2(h); }
__device__ __forceinline__ __half2 f2h(float2 f) { return __float22half2_rn(f); }

// Wave-level ordering fence: LDS ops of a wave execute in order on the DS
// pipe; this only stops compiler reordering (no s_barrier, no cnt drain).
__device__ __forceinline__ void wave_sync() {
  asm volatile("" ::: "memory");
  __builtin_amdgcn_wave_barrier();
  asm volatile("" ::: "memory");
}

// radix-4 DIF butterfly
__device__ __forceinline__ void r4bf(float2 a, float2 b, float2 c, float2 d,
                                     float2& y0, float2& t1, float2& t2, float2& t3) {
  float2 apc = make_float2(a.x + c.x, a.y + c.y);
  float2 amc = make_float2(a.x - c.x, a.y - c.y);
  float2 bpd = make_float2(b.x + d.x, b.y + d.y);
  float2 bmd = make_float2(b.x - d.x, b.y - d.y);
  y0 = make_float2(apc.x + bpd.x, apc.y + bpd.y);
  t1 = make_float2(amc.x + bmd.y, amc.y - bmd.x);  // amc - i*bmd
  t2 = make_float2(apc.x - bpd.x, apc.y - bpd.y);
  t3 = make_float2(amc.x - bmd.y, amc.y + bmd.x);  // amc + i*bmd
}

struct TW {
  float2 a1, a2, a3, b1, b2, b3, c1, c2, c3;
};

__device__ __forceinline__ void load_tw(const float2* __restrict__ W256f, int lane, TW& t) {
  t.a1 = W256f[lane];     t.a2 = W256f[2 * lane];  t.a3 = W256f[3 * lane];
  int p1 = 4 * (lane >> 2);
  t.b1 = W256f[p1];       t.b2 = W256f[2 * p1];    t.b3 = W256f[3 * p1];
  int p2 = 16 * (lane >> 4);
  t.c1 = W256f[p2];       t.c2 = W256f[2 * p2];    t.c3 = W256f[3 * p2];
}

// 256-pt forward complex FFT. Input regs z0..z3 = z[lane+64m]; output regs
// z0..z3 = Z[lane+64m]. Stages 0 & 3 in registers; 1 & 2 via wave-private LDS.
__device__ __forceinline__ void fft256_reg(float2& z0, float2& z1, float2& z2, float2& z3,
                                           float2* __restrict__ buf, int lane, const TW& tw) {
  float2 y0, t1, t2, t3;
  // stage 0 (s=1, p=lane): pure register butterfly, scatter 4l..4l+3
  r4bf(z0, z1, z2, z3, y0, t1, t2, t3);
  int o0 = 4 * lane;
  buf[SWZ(o0)]     = y0;
  buf[SWZ(o0 + 1)] = cmul(tw.a1, t1);
  buf[SWZ(o0 + 2)] = cmul(tw.a2, t2);
  buf[SWZ(o0 + 3)] = cmul(tw.a3, t3);
  wave_sync();
  // stage 1 (s=4)
  {
    float2 a = buf[SWZ(lane)], b = buf[SWZ(lane + 64)],
           c = buf[SWZ(lane + 128)], d = buf[SWZ(lane + 192)];
    wave_sync();
    r4bf(a, b, c, d, y0, t1, t2, t3);
    int o = lane + 12 * (lane >> 2);
    buf[SWZ(o)]      = y0;
    buf[SWZ(o + 4)]  = cmul(tw.b1, t1);
    buf[SWZ(o + 8)]  = cmul(tw.b2, t2);
    buf[SWZ(o + 12)] = cmul(tw.b3, t3);
  }
  wave_sync();
  // stage 2 (s=16)
  {
    float2 a = buf[SWZ(lane)], b = buf[SWZ(lane + 64)],
           c = buf[SWZ(lane + 128)], d = buf[SWZ(lane + 192)];
    wave_sync();
    r4bf(a, b, c, d, y0, t1, t2, t3);
    int o = lane + 48 * (lane >> 4);
    buf[SWZ(o)]      = y0;
    buf[SWZ(o + 16)] = cmul(tw.c1, t1);
    buf[SWZ(o + 32)] = cmul(tw.c2, t2);
    buf[SWZ(o + 48)] = cmul(tw.c3, t3);
  }
  wave_sync();
  // stage 3 (s=64, p=0, twiddle-free): outputs land in register layout
  {
    float2 a = buf[SWZ(lane)], b = buf[SWZ(lane + 64)],
           c = buf[SWZ(lane + 128)], d = buf[SWZ(lane + 192)];
    wave_sync();
    r4bf(a, b, c, d, z0, z1, z2, z3);
  }
}

// W256f[m] = exp(-2pi i m/256), m<256 ; W512s[k] = exp(-2pi i k/512), k<=256
__device__ __forceinline__ void build_tables(float2* W256f, float2* W512s) {
  int tid = threadIdx.x;
  float sv, cv;
  __sincosf(-(TWOPI / 256.0f) * (float)tid, &sv, &cv);
  W256f[tid] = make_float2(cv, sv);
  __sincosf(-(TWOPI / 512.0f) * (float)tid, &sv, &cv);
  W512s[tid] = make_float2(cv, sv);
  if (tid == 0) W512s[256] = make_float2(-1.f, 0.f);
}

// ---------------------------------------------------------------------------
// 1) channel mix: y[b,d,t] = sum_c x[b,c,t] * mixer[c,d]   (fp16 output)
//    mixer read directly from global with wave-uniform indices -> scalar
//    loads through the constant cache (no LDS broadcast traffic).
// ---------------------------------------------------------------------------
__global__ __launch_bounds__(256) void mix_kernel(const float* __restrict__ x,
                                                  const float* __restrict__ mixer,
                                                  __half2* __restrict__ y) {
  int b = blockIdx.y;
  int t2 = blockIdx.x * 256 + threadIdx.x;     // float2-pair index
  const float2* xv = (const float2*)x;
  float2 xr[NCH];
#pragma unroll
  for (int c = 0; c < NCH; c++)
    xr[c] = xv[(((size_t)(b * NCH + c)) * T_LEN >> 1) + t2];
#pragma unroll 4
  for (int d = 0; d < NCH; d++) {
    float ax = 0.f, ay = 0.f;
#pragma unroll
    for (int c = 0; c < NCH; c++) {
      float m = mixer[c * NCH + d];            // uniform -> s_load
      ax = fmaf(xr[c].x, m, ax);
      ay = fmaf(xr[c].y, m, ay);
    }
    y[(((size_t)(b * NCH + d)) * T_LEN >> 1) + t2] = f2h(make_float2(ax, ay));
  }
}

// ---------------------------------------------------------------------------
// 2) forward rfft(512) + register-local scan. Wave = one 4-frame chunk.
//    y and spec in fp16.  (R6-exact)
// ---------------------------------------------------------------------------
__global__ __launch_bounds__(256, 4) void fft_fwd_kernel(const __half2* __restrict__ y,
                                                         const float* __restrict__ transfer,
                                                         __half2* __restrict__ spec) {
  __shared__ float2 fbuf[4][NBIN];       // wave-private FFT/mirror buffer
  __shared__ float2 W256f[256];
  __shared__ float2 W512s[NBIN];
  build_tables(W256f, W512s);
  __syncthreads();
  int wave = threadIdx.x >> 6, lane = threadIdx.x & 63;
  int cid = blockIdx.x * 4 + wave;       // chunk id 0..16383
  int bc = cid >> 7, blk = cid & (NBLK - 1);
  int ch = bc & (NCH - 1);
  float2* buf = fbuf[wave];
  TW tw; load_tw(W256f, lane, tw);
  float cwq[4], swq[4], trq[4];
#pragma unroll
  for (int q = 0; q < 4; q++) {
    int k = lane + 64 * q;
    cwq[q] = W512s[k].x; swq[q] = W512s[k].y;
    trq[q] = transfer[ch * NBIN + k];
  }
  float tr256 = transfer[ch * NBIN + 256];
  float2 s[4] = {make_float2(0,0), make_float2(0,0), make_float2(0,0), make_float2(0,0)};
  float s256x = 0.f;
  size_t base2 = ((size_t)bc * T_LEN + (size_t)blk * (FPB * HOP)) >> 1;  // half2 idx
  size_t fb = ((size_t)bc * NFR + (size_t)blk * FPB) * NBIN;
  bool lastchunk = (blk == NBLK - 1);
#pragma unroll
  for (int j = 0; j < FPB; ++j) {
    const __half2* src = y + base2 + (size_t)j * (HOP / 2);
    // pack: z[n] = (y[2n], y[2n+1]) for n = lane+64q — one half2 load each
    float2 z0 = h2f(src[lane]);
    float2 z1 = h2f(src[lane + 64]);
    float2 z2, z3;
    if (lastchunk && j == FPB - 1) {     // zero-padded final half-window
      z2 = make_float2(0, 0); z3 = make_float2(0, 0);
    } else {
      z2 = h2f(src[lane + 128]);
      z3 = h2f(src[lane + 192]);
    }
    fft256_reg(z0, z1, z2, z3, buf, lane, tw);
    // stage Z (regs) for mirror access
    buf[lane] = z0; buf[lane + 64] = z1; buf[lane + 128] = z2; buf[lane + 192] = z3;
    wave_sync();
    float2 zm0 = buf[(256 - lane) & 255];
    float2 zm1 = buf[192 - lane];
    float2 zm2 = buf[128 - lane];
    float2 zm3 = buf[64 - lane];
    float2 z0b = buf[0];
    wave_sync();
    // untangle + scan + store, k = lane + 64q
#pragma unroll
    for (int q = 0; q < 4; q++) {
      float2 zk  = (q == 0) ? z0 : (q == 1) ? z1 : (q == 2) ? z2 : z3;
      float2 zmk = (q == 0) ? zm0 : (q == 1) ? zm1 : (q == 2) ? zm2 : zm3;
      float Ex = 0.5f * (zk.x + zmk.x), Ey = 0.5f * (zk.y - zmk.y);
      float dx = 0.5f * (zk.x - zmk.x), dy = 0.5f * (zk.y + zmk.y);
      float Ox = dy, Oy = -dx;
      float Yx = Ex + Ox * cwq[q] - Oy * swq[q];
      float Yy = Ey + Ox * swq[q] + Oy * cwq[q];
      s[q].x = trq[q] * (Yx + s[q].x);
      s[q].y = trq[q] * (Yy + s[q].y);
      spec[fb + (size_t)j * NBIN + lane + 64 * q] = f2h(s[q]);
    }
    // bin 256: zk = zmk = Z[0], cw=-1, sw=0 -> Y = (Z0.x - Z0.y, 0)
    s256x = tr256 * ((z0b.x - z0b.y) + s256x);
    if (lane == 0) spec[fb + (size_t)j * NBIN + 256] = f2h(make_float2(s256x, 0.f));
    wave_sync();
  }
}

// ---------------------------------------------------------------------------
// 3) carry scan across chunks: C[0]=0; C[i] = final[i-1] + tr^FPB * C[i-1]
//    (batch 16 for deeper MLP)
// ---------------------------------------------------------------------------
__global__ __launch_bounds__(256) void carry_kernel(const __half2* __restrict__ spec,
                                                    const float* __restrict__ transfer,
                                                    __half2* __restrict__ carries) {
  int tid = blockIdx.x * 256 + threadIdx.x;
  if (tid >= NBC * NBIN) return;
  int bc = tid / NBIN, k = tid - bc * NBIN;
  int ch = bc & (NCH - 1);
  float tr = transfer[ch * NBIN + k];
  float tr2 = tr * tr;
  float tr4 = tr2 * tr2;          // tr^FPB
  const __half2* fin = spec + (size_t)bc * NFR * NBIN + (size_t)(FPB - 1) * NBIN + k;
  __half2* cp = carries + (size_t)bc * NBLK * NBIN + k;
  float cx = 0.f, cy = 0.f;
  for (int i = 0; i < NBLK; i += 16) {
    float2 v[16];
#pragma unroll
    for (int u = 0; u < 16; u++) v[u] = h2f(fin[(size_t)(i + u) * FPB * NBIN]);
#pragma unroll
    for (int u = 0; u < 16; u++) {
      cp[(size_t)(i + u) * NBIN] = f2h(make_float2(cx, cy));
      cx = v[u].x + tr4 * cx;
      cy = v[u].y + tr4 * cy;
    }
  }
}

// ---------------------------------------------------------------------------
// 4) inverse rfft + hann + register OLA. Wave = one 4-frame chunk.
//    spec/carries/bnd in fp16; out in fp32.  (R6-exact)
// ---------------------------------------------------------------------------
__global__ __launch_bounds__(256, 4) void fft_inv_kernel(const __half2* __restrict__ spec,
                                                         const __half2* __restrict__ carries,
                                                         const float* __restrict__ transfer,
                                                         const float* __restrict__ gain,
                                                         float* __restrict__ out,
                                                         __half2* __restrict__ bnd) {
  __shared__ float2 fbuf[4][NBIN];
  __shared__ float2 W256f[256];
  __shared__ float2 W512s[NBIN];
  build_tables(W256f, W512s);
  __syncthreads();
  int wave = threadIdx.x >> 6, lane = threadIdx.x & 63;
  int cid = blockIdx.x * 4 + wave;
  int bc = cid >> 7, blk = cid & (NBLK - 1);
  int ch = bc & (NCH - 1);
  float2* buf = fbuf[wave];
  TW tw; load_tw(W256f, lane, tw);
  const __half2* crp = carries + ((size_t)bc * NBLK + blk) * NBIN;
  float cwq[4], swq[4], trq[4], trp[4], h0[4], h1[4];
  float2 cv[4];
#pragma unroll
  for (int q = 0; q < 4; q++) {
    int k = lane + 64 * q;
    cwq[q] = W512s[k].x; swq[q] = -W512s[k].y;   // exp(+2pi i k/512)
    trq[q] = transfer[ch * NBIN + k];
    trp[q] = trq[q];
    cv[q] = h2f(crp[k]);
    int t0 = 2 * k, t1 = 2 * k + 1;
    int i0 = (t0 <= 256) ? t0 : 512 - t0;
    int i1 = (t1 <= 256) ? t1 : 512 - t1;
    h0[q] = (0.5f - 0.5f * W512s[i0].x) * (1.0f / 256.0f);
    h1[q] = (0.5f - 0.5f * W512s[i1].x) * (1.0f / 256.0f);
  }
  float tr256 = transfer[ch * NBIN + 256], trp256 = tr256;
  float2 cv256 = h2f(crp[256]);
  float g = gain[ch];
  const __half2* sp0 = spec + ((size_t)bc * NFR + (size_t)blk * FPB) * NBIN;
  float2* outv = (float2*)out;
  size_t obase2 = ((size_t)bc * T_LEN + (size_t)blk * (FPB * HOP)) >> 1;
  __half2* bp = bnd + (((size_t)bc * NBLK + blk) * 2) * (HOP / 2);
  float2 pt0, pt1;                        // previous frame's windowed tail
#pragma unroll
  for (int j = 0; j < FPB; ++j) {
    const __half2* sp = sp0 + (size_t)j * NBIN;
    // load + carry fix-up: O = local + tr^(j+1) * carry
    float2 Y0 = h2f(sp[lane]);       Y0.x = fmaf(trp[0], cv[0].x, Y0.x); Y0.y = fmaf(trp[0], cv[0].y, Y0.y);
    float2 Y1 = h2f(sp[lane + 64]);  Y1.x = fmaf(trp[1], cv[1].x, Y1.x); Y1.y = fmaf(trp[1], cv[1].y, Y1.y);
    float2 Y2 = h2f(sp[lane + 128]); Y2.x = fmaf(trp[2], cv[2].x, Y2.x); Y2.y = fmaf(trp[2], cv[2].y, Y2.y);
    float2 Y3 = h2f(sp[lane + 192]); Y3.x = fmaf(trp[3], cv[3].x, Y3.x); Y3.y = fmaf(trp[3], cv[3].y, Y3.y);
    float2 y256 = h2f(sp[256]);
    y256.x = fmaf(trp256, cv256.x, y256.x);
    y256.y = fmaf(trp256, cv256.y, y256.y);
#pragma unroll
    for (int q = 0; q < 4; q++) trp[q] *= trq[q];
    trp256 *= tr256;
    // mirror staging
    buf[lane] = Y0; buf[lane + 64] = Y1; buf[lane + 128] = Y2; buf[lane + 192] = Y3;
    if (lane == 0) buf[256] = y256;
    wave_sync();
    float2 ym0 = buf[256 - lane];
    float2 ym1 = buf[192 - lane];
    float2 ym2 = buf[128 - lane];
    float2 ym3 = buf[64 - lane];
    wave_sync();
    // inverse untangle -> conj'd FFT input (register layout k = lane+64q)
    float2 z0, z1, z2, z3;
#pragma unroll
    for (int q = 0; q < 4; q++) {
      float2 yk  = (q == 0) ? Y0 : (q == 1) ? Y1 : (q == 2) ? Y2 : Y3;
      float2 ymk = (q == 0) ? ym0 : (q == 1) ? ym1 : (q == 2) ? ym2 : ym3;
      float Ex = 0.5f * (yk.x + ymk.x), Ey = 0.5f * (yk.y - ymk.y);
      float dx = 0.5f * (yk.x - ymk.x), dy = 0.5f * (yk.y + ymk.y);
      float Ox = dx * cwq[q] - dy * swq[q];
      float Oy = dx * swq[q] + dy * cwq[q];
      float2 zq = make_float2(Ex - Oy, -(Ey + Ox));
      if (q == 0) z0 = zq; else if (q == 1) z1 = zq; else if (q == 2) z2 = zq; else z3 = zq;
    }
    fft256_reg(z0, z1, z2, z3, buf, lane, tw);
    // windowed time samples: s = 2n, 2n+1 at n = lane+64q; x = conj/256
    float2 w0 = make_float2(z0.x * h0[0], -z0.y * h1[0]);
    float2 w1 = make_float2(z1.x * h0[1], -z1.y * h1[1]);
    float2 w2 = make_float2(z2.x * h0[2], -z2.y * h1[2]);
    float2 w3 = make_float2(z3.x * h0[3], -z3.y * h1[3]);
    if (j == 0) {
      bp[lane]      = f2h(w0);            // chunk-leading head -> bnd
      bp[lane + 64] = f2h(w1);
    } else {
      float2 v0 = make_float2(pt0.x + w0.x, pt0.y + w0.y);
      float2 v1 = make_float2(pt1.x + w1.x, pt1.y + w1.y);
      outv[obase2 + (size_t)j * 128 + lane] =
          make_float2(fast_tanh(g * v0.x), fast_tanh(g * v0.y));
      outv[obase2 + (size_t)j * 128 + lane + 64] =
          make_float2(fast_tanh(g * v1.x), fast_tanh(g * v1.y));
    }
    pt0 = w2; pt1 = w3;
    wave_sync();
  }
  bp[128 + lane] = f2h(pt0);              // chunk-trailing tail -> bnd
  bp[192 + lane] = f2h(pt1);
}

// ---------------------------------------------------------------------------
// 5) combine boundary chunks: chunk FPB*b <- bnd[b-1].tail + bnd[b].head
// ---------------------------------------------------------------------------
__global__ __launch_bounds__(256) void final_kernel(const __half* __restrict__ bnd,
                                                    const float* __restrict__ gain,
                                                    float* __restrict__ out) {
  int bc = blockIdx.y, b = blockIdx.x;
  int s = threadIdx.x;
  const __half* base = bnd + ((size_t)bc * NBLK) * 2 * HOP;
  float v = __half2float(base[((size_t)b * 2) * HOP + s]);
  if (b > 0) v += __half2float(base[((size_t)(b - 1) * 2 + 1) * HOP + s]);
  float g = gain[bc & (NCH - 1)];
  out[(size_t)bc * T_LEN + (size_t)b * (FPB * HOP) + s] = fast_tanh(g * v);
}

// ---------------------------------------------------------------------------
extern "C" void kernel_launch(void* const* d_in, const int* in_sizes, int n_in,
                              void* d_out, int out_size, void* d_ws, size_t ws_size,
                              hipStream_t stream) {
  (void)in_sizes; (void)n_in; (void)out_size; (void)ws_size;
  const float* x        = (const float*)d_in[0];
  const float* transfer = (const float*)d_in[1];
  const float* mixer    = (const float*)d_in[2];
  const float* gain     = (const float*)d_in[3];
  float* out = (float*)d_out;

  // ws layout (all fp16):
  //  [spec 67,371,008 B][bnd 16,777,216 B][carries 16,842,752 B][y 33,554,432 B]
  char* p = (char*)d_ws;
  __half2* spec    = (__half2*)p;                       p += (size_t)NBC * NFR * NBIN * 4;
  __half2* bnd     = (__half2*)p;                       p += (size_t)NBC * NBLK * 2 * HOP * 2;
  __half2* carries = (__half2*)p;                       p += (size_t)NBC * NBLK * NBIN * 4;
  __half2* y       = (__half2*)p;

  mix_kernel<<<dim3(T_LEN / 512, NBAT), 256, 0, stream>>>(x, mixer, y);
  fft_fwd_kernel<<<dim3(NBC * NBLK / 4), 256, 0, stream>>>(y, transfer, spec);
  carry_kernel<<<dim3((NBC * NBIN + 255) / 256), 256, 0, stream>>>(spec, transfer, carries);
  fft_inv_kernel<<<dim3(NBC * NBLK / 4), 256, 0, stream>>>(spec, carries, transfer, gain, out, (__half2*)bnd);
  final_kernel<<<dim3(NBLK, NBC), 256, 0, stream>>>((const __half*)bnd, gain, out);
}

// Round 13
// 118.260 us; speedup vs baseline: 1.4507x; 1.0164x over previous
//
#include <hip/hip_runtime.h>
#include <hip/hip_fp16.h>
#include <math.h>

// Problem constants
#define T_LEN 131072
#define NCH   32
#define NBAT  4
#define WIN   512
#define HOP   256
#define NFR   512            // frames per (b,c) = T/HOP
#define NBIN  257            // rfft bins
#define NBC   (NBAT*NCH)     // 128
#define FPB   4              // frames per chunk (one wave per chunk)
#define NBLK  (NFR/FPB)      // 128 chunks per bc
#define TWOPI 6.28318530717958647692f

// XOR swizzle for FFT LDS float2 arrays (hits the b64 4-lane/bank floor)
#define SWZ(m) ((m) ^ ((((m) >> 4) & 15)))

__device__ __forceinline__ float2 cmul(float2 u, float2 v) {
  return make_float2(fmaf(u.x, v.x, -u.y * v.y), fmaf(u.x, v.y, u.y * v.x));
}

__device__ __forceinline__ float fast_tanh(float x) {
  float e = __expf(2.0f * x);                    // inf-safe
  return 1.0f - 2.0f * __builtin_amdgcn_rcpf(e + 1.0f);
}

__device__ __forceinline__ float2 h2f(__half2 h) { return __half22float2(h); }
__device__ __forceinline__ __half2 f2h(float2 f) { return __float22half2_rn(f); }

// Wave-level ordering fence: LDS ops of a wave execute in order on the DS
// pipe; this only stops compiler reordering (no s_barrier, no cnt drain).
__device__ __forceinline__ void wave_sync() {
  asm volatile("" ::: "memory");
  __builtin_amdgcn_wave_barrier();
  asm volatile("" ::: "memory");
}

// radix-4 DIF butterfly
__device__ __forceinline__ void r4bf(float2 a, float2 b, float2 c, float2 d,
                                     float2& y0, float2& t1, float2& t2, float2& t3) {
  float2 apc = make_float2(a.x + c.x, a.y + c.y);
  float2 amc = make_float2(a.x - c.x, a.y - c.y);
  float2 bpd = make_float2(b.x + d.x, b.y + d.y);
  float2 bmd = make_float2(b.x - d.x, b.y - d.y);
  y0 = make_float2(apc.x + bpd.x, apc.y + bpd.y);
  t1 = make_float2(amc.x + bmd.y, amc.y - bmd.x);  // amc - i*bmd
  t2 = make_float2(apc.x - bpd.x, apc.y - bpd.y);
  t3 = make_float2(amc.x - bmd.y, amc.y + bmd.x);  // amc + i*bmd
}

// Per-stage base twiddles only (6 VGPRs); w2, w3 recomputed inline to keep
// register pressure below the spill threshold (R11 post-mortem).
struct TW {
  float2 a1, b1, c1;
};

__device__ __forceinline__ void load_tw(const float2* __restrict__ W256f, int lane, TW& t) {
  t.a1 = W256f[lane];
  t.b1 = W256f[4 * (lane >> 2)];
  t.c1 = W256f[16 * (lane >> 4)];
}

// 256-pt forward complex FFT. Input regs z0..z3 = z[lane+64m]; output regs
// z0..z3 = Z[lane+64m]. Stages 0 & 3 in registers; 1 & 2 via wave-private LDS.
__device__ __forceinline__ void fft256_reg(float2& z0, float2& z1, float2& z2, float2& z3,
                                           float2* __restrict__ buf, int lane, const TW& tw) {
  float2 y0, t1, t2, t3;
  // stage 0 (s=1, p=lane): pure register butterfly, scatter 4l..4l+3
  r4bf(z0, z1, z2, z3, y0, t1, t2, t3);
  {
    float2 w1 = tw.a1, w2 = cmul(w1, w1), w3 = cmul(w1, w2);
    int o0 = 4 * lane;
    buf[SWZ(o0)]     = y0;
    buf[SWZ(o0 + 1)] = cmul(w1, t1);
    buf[SWZ(o0 + 2)] = cmul(w2, t2);
    buf[SWZ(o0 + 3)] = cmul(w3, t3);
  }
  wave_sync();
  // stage 1 (s=4)
  {
    float2 a = buf[SWZ(lane)], b = buf[SWZ(lane + 64)],
           c = buf[SWZ(lane + 128)], d = buf[SWZ(lane + 192)];
    wave_sync();
    r4bf(a, b, c, d, y0, t1, t2, t3);
    float2 w1 = tw.b1, w2 = cmul(w1, w1), w3 = cmul(w1, w2);
    int o = lane + 12 * (lane >> 2);
    buf[SWZ(o)]      = y0;
    buf[SWZ(o + 4)]  = cmul(w1, t1);
    buf[SWZ(o + 8)]  = cmul(w2, t2);
    buf[SWZ(o + 12)] = cmul(w3, t3);
  }
  wave_sync();
  // stage 2 (s=16)
  {
    float2 a = buf[SWZ(lane)], b = buf[SWZ(lane + 64)],
           c = buf[SWZ(lane + 128)], d = buf[SWZ(lane + 192)];
    wave_sync();
    r4bf(a, b, c, d, y0, t1, t2, t3);
    float2 w1 = tw.c1, w2 = cmul(w1, w1), w3 = cmul(w1, w2);
    int o = lane + 48 * (lane >> 4);
    buf[SWZ(o)]      = y0;
    buf[SWZ(o + 16)] = cmul(w1, t1);
    buf[SWZ(o + 32)] = cmul(w2, t2);
    buf[SWZ(o + 48)] = cmul(w3, t3);
  }
  wave_sync();
  // stage 3 (s=64, p=0, twiddle-free): outputs land in register layout
  {
    float2 a = buf[SWZ(lane)], b = buf[SWZ(lane + 64)],
           c = buf[SWZ(lane + 128)], d = buf[SWZ(lane + 192)];
    wave_sync();
    r4bf(a, b, c, d, z0, z1, z2, z3);
  }
}

// W256f[m] = exp(-2pi i m/256), m<256 ; W512s[k] = exp(-2pi i k/512), k<=256
__device__ __forceinline__ void build_tables(float2* W256f, float2* W512s) {
  int tid = threadIdx.x;
  float sv, cv;
  __sincosf(-(TWOPI / 256.0f) * (float)tid, &sv, &cv);
  W256f[tid] = make_float2(cv, sv);
  __sincosf(-(TWOPI / 512.0f) * (float)tid, &sv, &cv);
  W512s[tid] = make_float2(cv, sv);
  if (tid == 0) W512s[256] = make_float2(-1.f, 0.f);
}

// ---------------------------------------------------------------------------
// 1) channel mix: y[b,d,t] = sum_c x[b,c,t] * mixer[c,d]   (fp16 output)
//    mixer read directly (wave-uniform -> scalar loads via K$).
// ---------------------------------------------------------------------------
__global__ __launch_bounds__(256) void mix_kernel(const float* __restrict__ x,
                                                  const float* __restrict__ mixer,
                                                  __half2* __restrict__ y) {
  int b = blockIdx.y;
  int t2 = blockIdx.x * 256 + threadIdx.x;     // float2-pair index
  const float2* xv = (const float2*)x;
  float2 xr[NCH];
#pragma unroll
  for (int c = 0; c < NCH; c++)
    xr[c] = xv[(((size_t)(b * NCH + c)) * T_LEN >> 1) + t2];
#pragma unroll 4
  for (int d = 0; d < NCH; d++) {
    float ax = 0.f, ay = 0.f;
#pragma unroll
    for (int c = 0; c < NCH; c++) {
      float m = mixer[c * NCH + d];            // uniform -> s_load
      ax = fmaf(xr[c].x, m, ax);
      ay = fmaf(xr[c].y, m, ay);
    }
    y[(((size_t)(b * NCH + d)) * T_LEN >> 1) + t2] = f2h(make_float2(ax, ay));
  }
}

// ---------------------------------------------------------------------------
// 2) forward rfft(512) + register-local scan. Wave = one 4-frame chunk.
// ---------------------------------------------------------------------------
__global__ __launch_bounds__(256, 3) void fft_fwd_kernel(const __half2* __restrict__ y,
                                                         const float* __restrict__ transfer,
                                                         __half2* __restrict__ spec) {
  __shared__ float2 fbuf[4][NBIN];       // wave-private FFT/mirror buffer
  __shared__ float2 W256f[256];
  __shared__ float2 W512s[NBIN];
  build_tables(W256f, W512s);
  __syncthreads();
  int wave = threadIdx.x >> 6, lane = threadIdx.x & 63;
  int cid = blockIdx.x * 4 + wave;       // chunk id 0..16383
  int bc = cid >> 7, blk = cid & (NBLK - 1);
  int ch = bc & (NCH - 1);
  float2* buf = fbuf[wave];
  TW tw; load_tw(W256f, lane, tw);
  float cwq[4], swq[4], trq[4];
#pragma unroll
  for (int q = 0; q < 4; q++) {
    int k = lane + 64 * q;
    cwq[q] = W512s[k].x; swq[q] = W512s[k].y;
    trq[q] = transfer[ch * NBIN + k];
  }
  float tr256 = transfer[ch * NBIN + 256];
  float2 s[4] = {make_float2(0,0), make_float2(0,0), make_float2(0,0), make_float2(0,0)};
  float s256x = 0.f;
  size_t base2 = ((size_t)bc * T_LEN + (size_t)blk * (FPB * HOP)) >> 1;  // half2 idx
  size_t fb = ((size_t)bc * NFR + (size_t)blk * FPB) * NBIN;
  bool lastchunk = (blk == NBLK - 1);
#pragma unroll
  for (int j = 0; j < FPB; ++j) {
    const __half2* src = y + base2 + (size_t)j * (HOP / 2);
    // pack: z[n] = (y[2n], y[2n+1]) for n = lane+64q — one half2 load each
    float2 z0 = h2f(src[lane]);
    float2 z1 = h2f(src[lane + 64]);
    float2 z2, z3;
    if (lastchunk && j == FPB - 1) {     // zero-padded final half-window
      z2 = make_float2(0, 0); z3 = make_float2(0, 0);
    } else {
      z2 = h2f(src[lane + 128]);
      z3 = h2f(src[lane + 192]);
    }
    fft256_reg(z0, z1, z2, z3, buf, lane, tw);
    // stage Z (regs) for mirror access
    buf[lane] = z0; buf[lane + 64] = z1; buf[lane + 128] = z2; buf[lane + 192] = z3;
    wave_sync();
    float2 zm0 = buf[(256 - lane) & 255];
    float2 zm1 = buf[192 - lane];
    float2 zm2 = buf[128 - lane];
    float2 zm3 = buf[64 - lane];
    float2 z0b = buf[0];
    wave_sync();
    // untangle + scan + store, k = lane + 64q
#pragma unroll
    for (int q = 0; q < 4; q++) {
      float2 zk  = (q == 0) ? z0 : (q == 1) ? z1 : (q == 2) ? z2 : z3;
      float2 zmk = (q == 0) ? zm0 : (q == 1) ? zm1 : (q == 2) ? zm2 : zm3;
      float Ex = 0.5f * (zk.x + zmk.x), Ey = 0.5f * (zk.y - zmk.y);
      float dx = 0.5f * (zk.x - zmk.x), dy = 0.5f * (zk.y + zmk.y);
      float Ox = dy, Oy = -dx;
      float Yx = Ex + Ox * cwq[q] - Oy * swq[q];
      float Yy = Ey + Ox * swq[q] + Oy * cwq[q];
      s[q].x = trq[q] * (Yx + s[q].x);
      s[q].y = trq[q] * (Yy + s[q].y);
      spec[fb + (size_t)j * NBIN + lane + 64 * q] = f2h(s[q]);
    }
    // bin 256: zk = zmk = Z[0], cw=-1, sw=0 -> Y = (Z0.x - Z0.y, 0)
    s256x = tr256 * ((z0b.x - z0b.y) + s256x);
    if (lane == 0) spec[fb + (size_t)j * NBIN + 256] = f2h(make_float2(s256x, 0.f));
    wave_sync();
  }
}

// ---------------------------------------------------------------------------
// 3) carry scan across chunks: C[0]=0; C[i] = final[i-1] + tr^FPB * C[i-1]
// ---------------------------------------------------------------------------
__global__ __launch_bounds__(256) void carry_kernel(const __half2* __restrict__ spec,
                                                    const float* __restrict__ transfer,
                                                    __half2* __restrict__ carries) {
  int tid = blockIdx.x * 256 + threadIdx.x;
  if (tid >= NBC * NBIN) return;
  int bc = tid / NBIN, k = tid - bc * NBIN;
  int ch = bc & (NCH - 1);
  float tr = transfer[ch * NBIN + k];
  float tr2 = tr * tr;
  float tr4 = tr2 * tr2;          // tr^FPB
  const __half2* fin = spec + (size_t)bc * NFR * NBIN + (size_t)(FPB - 1) * NBIN + k;
  __half2* cp = carries + (size_t)bc * NBLK * NBIN + k;
  float cx = 0.f, cy = 0.f;
  for (int i = 0; i < NBLK; i += 16) {
    float2 v[16];
#pragma unroll
    for (int u = 0; u < 16; u++) v[u] = h2f(fin[(size_t)(i + u) * FPB * NBIN]);
#pragma unroll
    for (int u = 0; u < 16; u++) {
      cp[(size_t)(i + u) * NBIN] = f2h(make_float2(cx, cy));
      cx = v[u].x + tr4 * cx;
      cy = v[u].y + tr4 * cy;
    }
  }
}

// ---------------------------------------------------------------------------
// 4) inverse rfft + hann + register OLA. Wave = one 4-frame chunk.
// ---------------------------------------------------------------------------
__global__ __launch_bounds__(256, 3) void fft_inv_kernel(const __half2* __restrict__ spec,
                                                         const __half2* __restrict__ carries,
                                                         const float* __restrict__ transfer,
                                                         const float* __restrict__ gain,
                                                         float* __restrict__ out,
                                                         __half2* __restrict__ bnd) {
  __shared__ float2 fbuf[4][NBIN];
  __shared__ float2 W256f[256];
  __shared__ float2 W512s[NBIN];
  build_tables(W256f, W512s);
  __syncthreads();
  int wave = threadIdx.x >> 6, lane = threadIdx.x & 63;
  int cid = blockIdx.x * 4 + wave;
  int bc = cid >> 7, blk = cid & (NBLK - 1);
  int ch = bc & (NCH - 1);
  float2* buf = fbuf[wave];
  TW tw; load_tw(W256f, lane, tw);
  const __half2* crp = carries + ((size_t)bc * NBLK + blk) * NBIN;
  float cwq[4], swq[4], trq[4], trp[4], h0[4], h1[4];
  float2 cv[4];
#pragma unroll
  for (int q = 0; q < 4; q++) {
    int k = lane + 64 * q;
    cwq[q] = W512s[k].x; swq[q] = -W512s[k].y;   // exp(+2pi i k/512)
    trq[q] = transfer[ch * NBIN + k];
    trp[q] = trq[q];
    cv[q] = h2f(crp[k]);
    int t0 = 2 * k, t1 = 2 * k + 1;
    int i0 = (t0 <= 256) ? t0 : 512 - t0;
    int i1 = (t1 <= 256) ? t1 : 512 - t1;
    h0[q] = (0.5f - 0.5f * W512s[i0].x) * (1.0f / 256.0f);
    h1[q] = (0.5f - 0.5f * W512s[i1].x) * (1.0f / 256.0f);
  }
  float tr256 = transfer[ch * NBIN + 256], trp256 = tr256;
  float2 cv256 = h2f(crp[256]);
  float g = gain[ch];
  const __half2* sp0 = spec + ((size_t)bc * NFR + (size_t)blk * FPB) * NBIN;
  float2* outv = (float2*)out;
  size_t obase2 = ((size_t)bc * T_LEN + (size_t)blk * (FPB * HOP)) >> 1;
  __half2* bp = bnd + (((size_t)bc * NBLK + blk) * 2) * (HOP / 2);
  float2 pt0, pt1;                        // previous frame's windowed tail
#pragma unroll
  for (int j = 0; j < FPB; ++j) {
    const __half2* sp = sp0 + (size_t)j * NBIN;
    // load + carry fix-up: O = local + tr^(j+1) * carry
    float2 Y0 = h2f(sp[lane]);       Y0.x = fmaf(trp[0], cv[0].x, Y0.x); Y0.y = fmaf(trp[0], cv[0].y, Y0.y);
    float2 Y1 = h2f(sp[lane + 64]);  Y1.x = fmaf(trp[1], cv[1].x, Y1.x); Y1.y = fmaf(trp[1], cv[1].y, Y1.y);
    float2 Y2 = h2f(sp[lane + 128]); Y2.x = fmaf(trp[2], cv[2].x, Y2.x); Y2.y = fmaf(trp[2], cv[2].y, Y2.y);
    float2 Y3 = h2f(sp[lane + 192]); Y3.x = fmaf(trp[3], cv[3].x, Y3.x); Y3.y = fmaf(trp[3], cv[3].y, Y3.y);
    float2 y256 = h2f(sp[256]);
    y256.x = fmaf(trp256, cv256.x, y256.x);
    y256.y = fmaf(trp256, cv256.y, y256.y);
#pragma unroll
    for (int q = 0; q < 4; q++) trp[q] *= trq[q];
    trp256 *= tr256;
    // mirror staging
    buf[lane] = Y0; buf[lane + 64] = Y1; buf[lane + 128] = Y2; buf[lane + 192] = Y3;
    if (lane == 0) buf[256] = y256;
    wave_sync();
    float2 ym0 = buf[256 - lane];
    float2 ym1 = buf[192 - lane];
    float2 ym2 = buf[128 - lane];
    float2 ym3 = buf[64 - lane];
    wave_sync();
    // inverse untangle -> conj'd FFT input (register layout k = lane+64q)
    float2 z0, z1, z2, z3;
#pragma unroll
    for (int q = 0; q < 4; q++) {
      float2 yk  = (q == 0) ? Y0 : (q == 1) ? Y1 : (q == 2) ? Y2 : Y3;
      float2 ymk = (q == 0) ? ym0 : (q == 1) ? ym1 : (q == 2) ? ym2 : ym3;
      float Ex = 0.5f * (yk.x + ymk.x), Ey = 0.5f * (yk.y - ymk.y);
      float dx = 0.5f * (yk.x - ymk.x), dy = 0.5f * (yk.y + ymk.y);
      float Ox = dx * cwq[q] - dy * swq[q];
      float Oy = dx * swq[q] + dy * cwq[q];
      float2 zq = make_float2(Ex - Oy, -(Ey + Ox));
      if (q == 0) z0 = zq; else if (q == 1) z1 = zq; else if (q == 2) z2 = zq; else z3 = zq;
    }
    fft256_reg(z0, z1, z2, z3, buf, lane, tw);
    // windowed time samples: s = 2n, 2n+1 at n = lane+64q; x = conj/256
    float2 w0 = make_float2(z0.x * h0[0], -z0.y * h1[0]);
    float2 w1 = make_float2(z1.x * h0[1], -z1.y * h1[1]);
    float2 w2 = make_float2(z2.x * h0[2], -z2.y * h1[2]);
    float2 w3 = make_float2(z3.x * h0[3], -z3.y * h1[3]);
    if (j == 0) {
      bp[lane]      = f2h(w0);            // chunk-leading head -> bnd
      bp[lane + 64] = f2h(w1);
    } else {
      float2 v0 = make_float2(pt0.x + w0.x, pt0.y + w0.y);
      float2 v1 = make_float2(pt1.x + w1.x, pt1.y + w1.y);
      outv[obase2 + (size_t)j * 128 + lane] =
          make_float2(fast_tanh(g * v0.x), fast_tanh(g * v0.y));
      outv[obase2 + (size_t)j * 128 + lane + 64] =
          make_float2(fast_tanh(g * v1.x), fast_tanh(g * v1.y));
    }
    pt0 = w2; pt1 = w3;
    wave_sync();
  }
  bp[128 + lane] = f2h(pt0);              // chunk-trailing tail -> bnd
  bp[192 + lane] = f2h(pt1);
}

// ---------------------------------------------------------------------------
// 5) combine boundary chunks: chunk FPB*b <- bnd[b-1].tail + bnd[b].head
// ---------------------------------------------------------------------------
__global__ __launch_bounds__(256) void final_kernel(const __half* __restrict__ bnd,
                                                    const float* __restrict__ gain,
                                                    float* __restrict__ out) {
  int bc = blockIdx.y, b = blockIdx.x;
  int s = threadIdx.x;
  const __half* base = bnd + ((size_t)bc * NBLK) * 2 * HOP;
  float v = __half2float(base[((size_t)b * 2) * HOP + s]);
  if (b > 0) v += __half2float(base[((size_t)(b - 1) * 2 + 1) * HOP + s]);
  float g = gain[bc & (NCH - 1)];
  out[(size_t)bc * T_LEN + (size_t)b * (FPB * HOP) + s] = fast_tanh(g * v);
}

// ---------------------------------------------------------------------------
extern "C" void kernel_launch(void* const* d_in, const int* in_sizes, int n_in,
                              void* d_out, int out_size, void* d_ws, size_t ws_size,
                              hipStream_t stream) {
  (void)in_sizes; (void)n_in; (void)out_size; (void)ws_size;
  const float* x        = (const float*)d_in[0];
  const float* transfer = (const float*)d_in[1];
  const float* mixer    = (const float*)d_in[2];
  const float* gain     = (const float*)d_in[3];
  float* out = (float*)d_out;

  // ws layout (all fp16):
  //  [spec 67,371,008 B][bnd 16,777,216 B][carries 16,842,752 B][y 33,554,432 B]
  char* p = (char*)d_ws;
  __half2* spec    = (__half2*)p;                       p += (size_t)NBC * NFR * NBIN * 4;
  __half2* bnd     = (__half2*)p;                       p += (size_t)NBC * NBLK * 2 * HOP * 2;
  __half2* carries = (__half2*)p;                       p += (size_t)NBC * NBLK * NBIN * 4;
  __half2* y       = (__half2*)p;

  mix_kernel<<<dim3(T_LEN / 512, NBAT), 256, 0, stream>>>(x, mixer, y);
  fft_fwd_kernel<<<dim3(NBC * NBLK / 4), 256, 0, stream>>>(y, transfer, spec);
  carry_kernel<<<dim3((NBC * NBIN + 255) / 256), 256, 0, stream>>>(spec, transfer, carries);
  fft_inv_kernel<<<dim3(NBC * NBLK / 4), 256, 0, stream>>>(spec, carries, transfer, gain, out, (__half2*)bnd);
  final_kernel<<<dim3(NBLK, NBC), 256, 0, stream>>>((const __half*)bnd, gain, out);
}

// Round 14
// 113.793 us; speedup vs baseline: 1.5077x; 1.0393x over previous
//
#include <hip/hip_runtime.h>
#include <hip/hip_fp16.h>
#include <math.h>

// Problem constants
#define T_LEN 131072
#define NCH   32
#define NBAT  4
#define WIN   512
#define HOP   256
#define NFR   512            // frames per (b,c) = T/HOP
#define NBIN  257            // rfft bins
#define NBC   (NBAT*NCH)     // 128
#define FPB   4              // frames per chunk (one wave per chunk)
#define NBLK  (NFR/FPB)      // 128 chunks per bc
#define TWOPI 6.28318530717958647692f

// XOR swizzle for FFT LDS complex arrays (hits the b64 4-lane/bank floor)
#define SWZ(m) ((m) ^ ((((m) >> 4) & 15)))

// Packed complex type: clang emits v_pk_{add,mul,fma}_f32 for ext_vector
// float2 arithmetic on CDNA — halves VALU instruction count vs scalar pairs.
typedef float v2f __attribute__((ext_vector_type(2)));

__device__ __forceinline__ v2f cmulv(v2f u, v2f v) {
  // (ux vx - uy vy, ux vy + uy vx) = u.xx*v + (-uy, uy)*v.yx  -> 2 pk_fma
  v2f r = u.xx * v;
  return __builtin_elementwise_fma((v2f){-u.y, u.y}, v.yx, r);
}

__device__ __forceinline__ float fast_tanh(float x) {
  float e = __expf(2.0f * x);                    // inf-safe
  return 1.0f - 2.0f * __builtin_amdgcn_rcpf(e + 1.0f);
}

__device__ __forceinline__ v2f h2v(__half2 h) {
  float2 f = __half22float2(h);
  return (v2f){f.x, f.y};
}
__device__ __forceinline__ __half2 v2h(v2f v) {
  return __float22half2_rn(make_float2(v.x, v.y));
}

// Wave-level ordering fence: LDS ops of a wave execute in order on the DS
// pipe; this only stops compiler reordering (no s_barrier, no cnt drain).
__device__ __forceinline__ void wave_sync() {
  asm volatile("" ::: "memory");
  __builtin_amdgcn_wave_barrier();
  asm volatile("" ::: "memory");
}

// radix-4 DIF butterfly (packed): t1 = amc - i*bmd, t3 = amc + i*bmd
__device__ __forceinline__ void r4bf(v2f a, v2f b, v2f c, v2f d,
                                     v2f& y0, v2f& t1, v2f& t2, v2f& t3) {
  const v2f PM = {1.f, -1.f};
  const v2f MP = {-1.f, 1.f};
  v2f apc = a + c, amc = a - c;
  v2f bpd = b + d, bmd = b - d;
  y0 = apc + bpd;
  t2 = apc - bpd;
  v2f bs = bmd.yx;
  t1 = __builtin_elementwise_fma(bs, PM, amc);   // (amc.x+bmd.y, amc.y-bmd.x)
  t3 = __builtin_elementwise_fma(bs, MP, amc);   // (amc.x-bmd.y, amc.y+bmd.x)
}

// Per-stage base twiddles only (6 VGPRs); w2, w3 recomputed inline (R11).
struct TW {
  v2f a1, b1, c1;
};

__device__ __forceinline__ void load_tw(const v2f* __restrict__ W256f, int lane, TW& t) {
  t.a1 = W256f[lane];
  t.b1 = W256f[4 * (lane >> 2)];
  t.c1 = W256f[16 * (lane >> 4)];
}

// 256-pt forward complex FFT. Input regs z0..z3 = z[lane+64m]; output regs
// z0..z3 = Z[lane+64m]. Stages 0 & 3 in registers; 1 & 2 via wave-private LDS.
__device__ __forceinline__ void fft256_reg(v2f& z0, v2f& z1, v2f& z2, v2f& z3,
                                           v2f* __restrict__ buf, int lane, const TW& tw) {
  v2f y0, t1, t2, t3;
  // stage 0 (s=1, p=lane): pure register butterfly, scatter 4l..4l+3
  r4bf(z0, z1, z2, z3, y0, t1, t2, t3);
  {
    v2f w1 = tw.a1, w2 = cmulv(w1, w1), w3 = cmulv(w1, w2);
    int o0 = 4 * lane;
    buf[SWZ(o0)]     = y0;
    buf[SWZ(o0 + 1)] = cmulv(w1, t1);
    buf[SWZ(o0 + 2)] = cmulv(w2, t2);
    buf[SWZ(o0 + 3)] = cmulv(w3, t3);
  }
  wave_sync();
  // stage 1 (s=4)
  {
    v2f a = buf[SWZ(lane)], b = buf[SWZ(lane + 64)],
        c = buf[SWZ(lane + 128)], d = buf[SWZ(lane + 192)];
    wave_sync();
    r4bf(a, b, c, d, y0, t1, t2, t3);
    v2f w1 = tw.b1, w2 = cmulv(w1, w1), w3 = cmulv(w1, w2);
    int o = lane + 12 * (lane >> 2);
    buf[SWZ(o)]      = y0;
    buf[SWZ(o + 4)]  = cmulv(w1, t1);
    buf[SWZ(o + 8)]  = cmulv(w2, t2);
    buf[SWZ(o + 12)] = cmulv(w3, t3);
  }
  wave_sync();
  // stage 2 (s=16)
  {
    v2f a = buf[SWZ(lane)], b = buf[SWZ(lane + 64)],
        c = buf[SWZ(lane + 128)], d = buf[SWZ(lane + 192)];
    wave_sync();
    r4bf(a, b, c, d, y0, t1, t2, t3);
    v2f w1 = tw.c1, w2 = cmulv(w1, w1), w3 = cmulv(w1, w2);
    int o = lane + 48 * (lane >> 4);
    buf[SWZ(o)]      = y0;
    buf[SWZ(o + 16)] = cmulv(w1, t1);
    buf[SWZ(o + 32)] = cmulv(w2, t2);
    buf[SWZ(o + 48)] = cmulv(w3, t3);
  }
  wave_sync();
  // stage 3 (s=64, p=0, twiddle-free): outputs land in register layout
  {
    v2f a = buf[SWZ(lane)], b = buf[SWZ(lane + 64)],
        c = buf[SWZ(lane + 128)], d = buf[SWZ(lane + 192)];
    wave_sync();
    r4bf(a, b, c, d, z0, z1, z2, z3);
  }
}

// W256f[m] = exp(-2pi i m/256), m<256 ; W512s[k] = exp(-2pi i k/512), k<=256
__device__ __forceinline__ void build_tables(v2f* W256f, v2f* W512s) {
  int tid = threadIdx.x;
  float sv, cv;
  __sincosf(-(TWOPI / 256.0f) * (float)tid, &sv, &cv);
  W256f[tid] = (v2f){cv, sv};
  __sincosf(-(TWOPI / 512.0f) * (float)tid, &sv, &cv);
  W512s[tid] = (v2f){cv, sv};
  if (tid == 0) W512s[256] = (v2f){-1.f, 0.f};
}

// ---------------------------------------------------------------------------
// 1) channel mix: y[b,d,t] = sum_c x[b,c,t] * mixer[c,d]   (fp16 output)
//    mixer read directly (wave-uniform -> scalar loads via K$).
// ---------------------------------------------------------------------------
__global__ __launch_bounds__(256) void mix_kernel(const float* __restrict__ x,
                                                  const float* __restrict__ mixer,
                                                  __half2* __restrict__ y) {
  int b = blockIdx.y;
  int t2 = blockIdx.x * 256 + threadIdx.x;     // float2-pair index
  const float2* xv = (const float2*)x;
  float2 xr[NCH];
#pragma unroll
  for (int c = 0; c < NCH; c++)
    xr[c] = xv[(((size_t)(b * NCH + c)) * T_LEN >> 1) + t2];
#pragma unroll 4
  for (int d = 0; d < NCH; d++) {
    float ax = 0.f, ay = 0.f;
#pragma unroll
    for (int c = 0; c < NCH; c++) {
      float m = mixer[c * NCH + d];            // uniform -> s_load
      ax = fmaf(xr[c].x, m, ax);
      ay = fmaf(xr[c].y, m, ay);
    }
    y[(((size_t)(b * NCH + d)) * T_LEN >> 1) + t2] = __float22half2_rn(make_float2(ax, ay));
  }
}

// ---------------------------------------------------------------------------
// 2) forward rfft(512) + register-local scan. Wave = one 4-frame chunk.
// ---------------------------------------------------------------------------
__global__ __launch_bounds__(256, 3) void fft_fwd_kernel(const __half2* __restrict__ y,
                                                         const float* __restrict__ transfer,
                                                         __half2* __restrict__ spec) {
  __shared__ v2f fbuf[4][NBIN];          // wave-private FFT/mirror buffer
  __shared__ v2f W256f[256];
  __shared__ v2f W512s[NBIN];
  build_tables(W256f, W512s);
  __syncthreads();
  const v2f PM = {1.f, -1.f};
  int wave = threadIdx.x >> 6, lane = threadIdx.x & 63;
  int cid = blockIdx.x * 4 + wave;       // chunk id 0..16383
  int bc = cid >> 7, blk = cid & (NBLK - 1);
  int ch = bc & (NCH - 1);
  v2f* buf = fbuf[wave];
  TW tw; load_tw(W256f, lane, tw);
  v2f Wf[4];
  float trq[4];
#pragma unroll
  for (int q = 0; q < 4; q++) {
    int k = lane + 64 * q;
    Wf[q] = W512s[k];                    // (cw, sw)
    trq[q] = transfer[ch * NBIN + k];
  }
  float tr256 = transfer[ch * NBIN + 256];
  v2f s[4] = {(v2f){0,0}, (v2f){0,0}, (v2f){0,0}, (v2f){0,0}};
  float s256x = 0.f;
  size_t base2 = ((size_t)bc * T_LEN + (size_t)blk * (FPB * HOP)) >> 1;  // half2 idx
  size_t fb = ((size_t)bc * NFR + (size_t)blk * FPB) * NBIN;
  bool lastchunk = (blk == NBLK - 1);
#pragma unroll
  for (int j = 0; j < FPB; ++j) {
    const __half2* src = y + base2 + (size_t)j * (HOP / 2);
    // pack: z[n] = (y[2n], y[2n+1]) for n = lane+64q — one half2 load each
    v2f z0 = h2v(src[lane]);
    v2f z1 = h2v(src[lane + 64]);
    v2f z2, z3;
    if (lastchunk && j == FPB - 1) {     // zero-padded final half-window
      z2 = (v2f){0, 0}; z3 = (v2f){0, 0};
    } else {
      z2 = h2v(src[lane + 128]);
      z3 = h2v(src[lane + 192]);
    }
    fft256_reg(z0, z1, z2, z3, buf, lane, tw);
    // stage Z (regs) for mirror access
    buf[lane] = z0; buf[lane + 64] = z1; buf[lane + 128] = z2; buf[lane + 192] = z3;
    wave_sync();
    v2f zm0 = buf[(256 - lane) & 255];
    v2f zm1 = buf[192 - lane];
    v2f zm2 = buf[128 - lane];
    v2f zm3 = buf[64 - lane];
    v2f z0b = buf[0];
    wave_sync();
    // untangle + scan + store, k = lane + 64q   (all packed)
#pragma unroll
    for (int q = 0; q < 4; q++) {
      v2f zk  = (q == 0) ? z0 : (q == 1) ? z1 : (q == 2) ? z2 : z3;
      v2f zmk = (q == 0) ? zm0 : (q == 1) ? zm1 : (q == 2) ? zm2 : zm3;
      v2f E = __builtin_elementwise_fma(zmk, PM, zk) * 0.5f;    // (zx+zmx, zy-zmy)/2
      v2f D = __builtin_elementwise_fma(zmk, -PM, zk) * 0.5f;   // (zx-zmx, zy+zmy)/2
      v2f O = D.yx * PM;                                        // (dy, -dx)
      v2f Y = E + cmulv(Wf[q], O);
      s[q] = (Y + s[q]) * trq[q];
      spec[fb + (size_t)j * NBIN + lane + 64 * q] = v2h(s[q]);
    }
    // bin 256: zk = zmk = Z[0], cw=-1, sw=0 -> Y = (Z0.x - Z0.y, 0)
    s256x = tr256 * ((z0b.x - z0b.y) + s256x);
    if (lane == 0) spec[fb + (size_t)j * NBIN + 256] = v2h((v2f){s256x, 0.f});
    wave_sync();
  }
}

// ---------------------------------------------------------------------------
// 3) carry scan across chunks: C[0]=0; C[i] = final[i-1] + tr^FPB * C[i-1]
// ---------------------------------------------------------------------------
__global__ __launch_bounds__(256) void carry_kernel(const __half2* __restrict__ spec,
                                                    const float* __restrict__ transfer,
                                                    __half2* __restrict__ carries) {
  int tid = blockIdx.x * 256 + threadIdx.x;
  if (tid >= NBC * NBIN) return;
  int bc = tid / NBIN, k = tid - bc * NBIN;
  int ch = bc & (NCH - 1);
  float tr = transfer[ch * NBIN + k];
  float tr2 = tr * tr;
  float tr4 = tr2 * tr2;          // tr^FPB
  const __half2* fin = spec + (size_t)bc * NFR * NBIN + (size_t)(FPB - 1) * NBIN + k;
  __half2* cp = carries + (size_t)bc * NBLK * NBIN + k;
  v2f c = {0.f, 0.f};
  for (int i = 0; i < NBLK; i += 16) {
    v2f v[16];
#pragma unroll
    for (int u = 0; u < 16; u++) v[u] = h2v(fin[(size_t)(i + u) * FPB * NBIN]);
#pragma unroll
    for (int u = 0; u < 16; u++) {
      cp[(size_t)(i + u) * NBIN] = v2h(c);
      c = __builtin_elementwise_fma((v2f){tr4, tr4}, c, v[u]);
    }
  }
}

// ---------------------------------------------------------------------------
// 4) inverse rfft + hann + register OLA. Wave = one 4-frame chunk.
// ---------------------------------------------------------------------------
__global__ __launch_bounds__(256, 3) void fft_inv_kernel(const __half2* __restrict__ spec,
                                                         const __half2* __restrict__ carries,
                                                         const float* __restrict__ transfer,
                                                         const float* __restrict__ gain,
                                                         float* __restrict__ out,
                                                         __half2* __restrict__ bnd) {
  __shared__ v2f fbuf[4][NBIN];
  __shared__ v2f W256f[256];
  __shared__ v2f W512s[NBIN];
  build_tables(W256f, W512s);
  __syncthreads();
  const v2f PM = {1.f, -1.f};
  int wave = threadIdx.x >> 6, lane = threadIdx.x & 63;
  int cid = blockIdx.x * 4 + wave;
  int bc = cid >> 7, blk = cid & (NBLK - 1);
  int ch = bc & (NCH - 1);
  v2f* buf = fbuf[wave];
  TW tw; load_tw(W256f, lane, tw);
  const __half2* crp = carries + ((size_t)bc * NBLK + blk) * NBIN;
  v2f Wi[4], cv[4], hv[4];
  float trq[4], trp[4];
#pragma unroll
  for (int q = 0; q < 4; q++) {
    int k = lane + 64 * q;
    Wi[q] = W512s[k] * PM;               // (cw, -sw) = exp(+2pi i k/512)
    trq[q] = transfer[ch * NBIN + k];
    trp[q] = trq[q];
    cv[q] = h2v(crp[k]);
    int t0 = 2 * k, t1 = 2 * k + 1;
    int i0 = (t0 <= 256) ? t0 : 512 - t0;
    int i1 = (t1 <= 256) ? t1 : 512 - t1;
    float h0 = (0.5f - 0.5f * W512s[i0].x) * (1.0f / 256.0f);
    float h1 = (0.5f - 0.5f * W512s[i1].x) * (1.0f / 256.0f);
    hv[q] = (v2f){h0, -h1};              // window + conj fold: w = z * (h0, -h1)
  }
  float tr256 = transfer[ch * NBIN + 256], trp256 = tr256;
  v2f cv256 = h2v(crp[256]);
  float g = gain[ch];
  const __half2* sp0 = spec + ((size_t)bc * NFR + (size_t)blk * FPB) * NBIN;
  float2* outv = (float2*)out;
  size_t obase2 = ((size_t)bc * T_LEN + (size_t)blk * (FPB * HOP)) >> 1;
  __half2* bp = bnd + (((size_t)bc * NBLK + blk) * 2) * (HOP / 2);
  v2f pt0, pt1;                          // previous frame's windowed tail
#pragma unroll
  for (int j = 0; j < FPB; ++j) {
    const __half2* sp = sp0 + (size_t)j * NBIN;
    // load + carry fix-up: O = local + tr^(j+1) * carry   (packed fma)
    v2f Y0 = __builtin_elementwise_fma((v2f){trp[0], trp[0]}, cv[0], h2v(sp[lane]));
    v2f Y1 = __builtin_elementwise_fma((v2f){trp[1], trp[1]}, cv[1], h2v(sp[lane + 64]));
    v2f Y2 = __builtin_elementwise_fma((v2f){trp[2], trp[2]}, cv[2], h2v(sp[lane + 128]));
    v2f Y3 = __builtin_elementwise_fma((v2f){trp[3], trp[3]}, cv[3], h2v(sp[lane + 192]));
    v2f y256 = __builtin_elementwise_fma((v2f){trp256, trp256}, cv256, h2v(sp[256]));
#pragma unroll
    for (int q = 0; q < 4; q++) trp[q] *= trq[q];
    trp256 *= tr256;
    // mirror staging
    buf[lane] = Y0; buf[lane + 64] = Y1; buf[lane + 128] = Y2; buf[lane + 192] = Y3;
    if (lane == 0) buf[256] = y256;
    wave_sync();
    v2f ym0 = buf[256 - lane];
    v2f ym1 = buf[192 - lane];
    v2f ym2 = buf[128 - lane];
    v2f ym3 = buf[64 - lane];
    wave_sync();
    // inverse untangle -> conj'd FFT input:  z = E*PM - O.yx   (packed)
    v2f z0, z1, z2, z3;
#pragma unroll
    for (int q = 0; q < 4; q++) {
      v2f yk  = (q == 0) ? Y0 : (q == 1) ? Y1 : (q == 2) ? Y2 : Y3;
      v2f ymk = (q == 0) ? ym0 : (q == 1) ? ym1 : (q == 2) ? ym2 : ym3;
      v2f E = __builtin_elementwise_fma(ymk, PM, yk) * 0.5f;
      v2f D = __builtin_elementwise_fma(ymk, -PM, yk) * 0.5f;
      v2f O = cmulv(Wi[q], D);           // (dx cw - dy sw, dx sw + dy cw)
      v2f zq = E * PM - O.yx;            // (Ex - Oy, -(Ey + Ox))
      if (q == 0) z0 = zq; else if (q == 1) z1 = zq; else if (q == 2) z2 = zq; else z3 = zq;
    }
    fft256_reg(z0, z1, z2, z3, buf, lane, tw);
    // windowed time samples: w = z * (h0, -h1)   (conj + /256 folded in)
    v2f w0 = z0 * hv[0];
    v2f w1 = z1 * hv[1];
    v2f w2 = z2 * hv[2];
    v2f w3 = z3 * hv[3];
    if (j == 0) {
      bp[lane]      = v2h(w0);           // chunk-leading head -> bnd
      bp[lane + 64] = v2h(w1);
    } else {
      v2f v0 = pt0 + w0;
      v2f v1 = pt1 + w1;
      outv[obase2 + (size_t)j * 128 + lane] =
          make_float2(fast_tanh(g * v0.x), fast_tanh(g * v0.y));
      outv[obase2 + (size_t)j * 128 + lane + 64] =
          make_float2(fast_tanh(g * v1.x), fast_tanh(g * v1.y));
    }
    pt0 = w2; pt1 = w3;
    wave_sync();
  }
  bp[128 + lane] = v2h(pt0);             // chunk-trailing tail -> bnd
  bp[192 + lane] = v2h(pt1);
}

// ---------------------------------------------------------------------------
// 5) combine boundary chunks: chunk FPB*b <- bnd[b-1].tail + bnd[b].head
// ---------------------------------------------------------------------------
__global__ __launch_bounds__(256) void final_kernel(const __half* __restrict__ bnd,
                                                    const float* __restrict__ gain,
                                                    float* __restrict__ out) {
  int bc = blockIdx.y, b = blockIdx.x;
  int s = threadIdx.x;
  const __half* base = bnd + ((size_t)bc * NBLK) * 2 * HOP;
  float v = __half2float(base[((size_t)b * 2) * HOP + s]);
  if (b > 0) v += __half2float(base[((size_t)(b - 1) * 2 + 1) * HOP + s]);
  float g = gain[bc & (NCH - 1)];
  out[(size_t)bc * T_LEN + (size_t)b * (FPB * HOP) + s] = fast_tanh(g * v);
}

// ---------------------------------------------------------------------------
extern "C" void kernel_launch(void* const* d_in, const int* in_sizes, int n_in,
                              void* d_out, int out_size, void* d_ws, size_t ws_size,
                              hipStream_t stream) {
  (void)in_sizes; (void)n_in; (void)out_size; (void)ws_size;
  const float* x        = (const float*)d_in[0];
  const float* transfer = (const float*)d_in[1];
  const float* mixer    = (const float*)d_in[2];
  const float* gain     = (const float*)d_in[3];
  float* out = (float*)d_out;

  // ws layout (all fp16):
  //  [spec 67,371,008 B][bnd 16,777,216 B][carries 16,842,752 B][y 33,554,432 B]
  char* p = (char*)d_ws;
  __half2* spec    = (__half2*)p;                       p += (size_t)NBC * NFR * NBIN * 4;
  __half2* bnd     = (__half2*)p;                       p += (size_t)NBC * NBLK * 2 * HOP * 2;
  __half2* carries = (__half2*)p;                       p += (size_t)NBC * NBLK * NBIN * 4;
  __half2* y       = (__half2*)p;

  mix_kernel<<<dim3(T_LEN / 512, NBAT), 256, 0, stream>>>(x, mixer, y);
  fft_fwd_kernel<<<dim3(NBC * NBLK / 4), 256, 0, stream>>>(y, transfer, spec);
  carry_kernel<<<dim3((NBC * NBIN + 255) / 256), 256, 0, stream>>>(spec, transfer, carries);
  fft_inv_kernel<<<dim3(NBC * NBLK / 4), 256, 0, stream>>>(spec, carries, transfer, gain, out, (__half2*)bnd);
  final_kernel<<<dim3(NBLK, NBC), 256, 0, stream>>>((const __half*)bnd, gain, out);
}